// Round 6
// baseline (446.288 us; speedup 1.0000x reference)
//
#include <hip/hip_runtime.h>
#include <hip/hip_fp16.h>

#define N_USERS 100000
#define N_ITEMS 50000
#define N_TOPICS 1000
#define N_NODES (N_USERS + N_ITEMS + N_TOPICS)   // 151000
#define DIM 64
#define NNZ 4000000
#define BATCH 16384

#define BROWS 128                                 // rows per bucket
#define NB ((N_NODES + BROWS - 1) / BROWS)        // 1180 buckets
#define NPART 256                                 // partition blocks
#define CHUNK ((NNZ + NPART - 1) / NPART)         // 15625 edges per block
#define SEGCAP 4608                               // LDS seg capacity (36 KB)

// cv entry: (qval14 << 18) | col18 ; val = qval * (1/16384)
#define QSCALE 16384.0f
#define QINV   6.103515625e-05f                   // 1/16384

#define CONCAT_TOTAL (N_NODES * (DIM / 4))        // 2,416,000
#define CONCAT_BLOCKS ((CONCAT_TOTAL + 1023) / 1024)   // 2360
#define BINIT_TOTAL (2 * BATCH * (DIM / 4))       // 524,288
#define BINIT_BLOCKS ((BINIT_TOTAL + 1023) / 1024)     // 512

// ---------------------------------------------------------------------------
// phase0: fused (part_count | concat_init | batch_init) by blockIdx role.
// Also zeroes the scanAB sync counter (re-zeroed on every graph replay).
// ---------------------------------------------------------------------------
__global__ void __launch_bounds__(1024)
phase0(const float4* __restrict__ uw,
       const float4* __restrict__ iw,
       const float4* __restrict__ tw,
       const int* __restrict__ row,
       const int* __restrict__ users,
       const int* __restrict__ items,
       __half2* __restrict__ x0,
       float4* __restrict__ accb,
       int* __restrict__ hcnt,
       int* __restrict__ sync) {
    __shared__ int h[NB];
    const int blk = blockIdx.x;
    const int t = threadIdx.x;
    if (blk < NPART) {
        // ---- part_count role ----
        if (blk == 0 && t == 0) *sync = 0;
        for (int i = t; i < NB; i += 1024) h[i] = 0;
        __syncthreads();
        int e0 = blk * CHUNK;
        int e1 = e0 + CHUNK; if (e1 > NNZ) e1 = NNZ;
        for (int e = e0 + t; e < e1; e += 1024) {
            int r = __builtin_nontemporal_load(&row[e]);
            atomicAdd(&h[r >> 7], 1);
        }
        __syncthreads();
        int* dst = hcnt + (size_t)blk * NB;
        for (int i = t; i < NB; i += 1024) dst[i] = h[i];
    } else if (blk < NPART + CONCAT_BLOCKS) {
        // ---- concat_init role ----
        int tid = (blk - NPART) * 1024 + t;
        if (tid >= CONCAT_TOTAL) return;
        int node = tid >> 4;
        int q = tid & 15;
        float4 v;
        if (node < N_USERS)                v = uw[node * 16 + q];
        else if (node < N_USERS + N_ITEMS) v = iw[(node - N_USERS) * 16 + q];
        else                               v = tw[(node - N_USERS - N_ITEMS) * 16 + q];
        x0[tid * 2]     = __floats2half2_rn(v.x, v.y);
        x0[tid * 2 + 1] = __floats2half2_rn(v.z, v.w);
    } else {
        // ---- batch_init role ----
        int tid = (blk - NPART - CONCAT_BLOCKS) * 1024 + t;
        if (tid >= BINIT_TOTAL) return;
        int r = tid >> 4;
        int q = tid & 15;
        float4 v;
        if (r < BATCH) v = uw[(size_t)users[r] * 16 + q];
        else           v = iw[(size_t)items[r - BATCH] * 16 + q];
        accb[tid] = v;
    }
}

// ---------------------------------------------------------------------------
// Fused scanA + scanB (last-block pattern). 295 blocks x 256 threads;
// each wave scans one bucket's column of hcnt across the NPART blocks.
// The last block to finish runs the NB-wide exclusive scan (scanB).
// ---------------------------------------------------------------------------
__global__ void __launch_bounds__(256)
part_scanAB(int* __restrict__ hcnt,
            int* __restrict__ bcnt,
            int* __restrict__ bptr,
            int* __restrict__ rowptr,
            int* __restrict__ sync) {
    const int t = threadIdx.x;
    const int lane = t & 63;
    const int wid = t >> 6;
    int b = blockIdx.x * 4 + wid;     // grid sized so b < NB always (1180/4=295)
    int carry = 0;
    for (int base = 0; base < NPART; base += 64) {
        int g = base + lane;
        int v = hcnt[(size_t)g * NB + b];
        int x = v;
        #pragma unroll
        for (int off = 1; off < 64; off <<= 1) {
            int y = __shfl_up(x, off, 64);
            if (lane >= off) x += y;
        }
        int tot = __shfl(x, 63, 64);
        hcnt[(size_t)g * NB + b] = carry + x - v;
        carry += tot;
    }
    if (lane == 0) bcnt[b] = carry;
    __syncthreads();
    __threadfence();
    __shared__ int lastFlag;
    if (t == 0) lastFlag = (atomicAdd(sync, 1) == (int)gridDim.x - 1);
    __syncthreads();
    if (!lastFlag) return;

    // ---- scanB over bcnt[0..NB) with 256 threads ----
    __shared__ int wsum[4];
    __shared__ int carry_s;
    if (t == 0) carry_s = 0;
    __syncthreads();
    for (int base = 0; base < NB; base += 256) {
        int i = base + t;
        int v = (i < NB) ? bcnt[i] : 0;
        int x = v;
        #pragma unroll
        for (int off = 1; off < 64; off <<= 1) {
            int y = __shfl_up(x, off, 64);
            if (lane >= off) x += y;
        }
        if (lane == 63) wsum[wid] = x;
        __syncthreads();
        int wbase = 0;
        for (int w = 0; w < wid; ++w) wbase += wsum[w];
        int excl = carry_s + wbase + (x - v);
        if (i < NB) bptr[i] = excl;
        __syncthreads();
        if (t == 255) carry_s = excl + v;
        __syncthreads();
    }
    if (t == 0) { bptr[NB] = NNZ; rowptr[N_NODES] = NNZ; }
}

// ---------------------------------------------------------------------------
// Partition phase 3: atomic-free scatter via per-(block,bucket) offsets.
// ---------------------------------------------------------------------------
__global__ void __launch_bounds__(1024)
part_scatter(const int* __restrict__ row,
             const int* __restrict__ col,
             const float* __restrict__ vals,
             const int* __restrict__ hcnt,
             const int* __restrict__ bptr,
             int2* __restrict__ cvtmp) {
    __shared__ int cur[NB];
    const int g = blockIdx.x;
    const int t = threadIdx.x;
    const int* hoff = hcnt + (size_t)g * NB;
    for (int i = t; i < NB; i += 1024) cur[i] = bptr[i] + hoff[i];
    __syncthreads();
    int e0 = g * CHUNK;
    int e1 = e0 + CHUNK; if (e1 > NNZ) e1 = NNZ;
    for (int e = e0 + t; e < e1; e += 1024) {
        int r = __builtin_nontemporal_load(&row[e]);
        int c = __builtin_nontemporal_load(&col[e]);
        float v = __builtin_nontemporal_load(&vals[e]);
        int p = atomicAdd(&cur[r >> 7], 1);
        cvtmp[p] = make_int2(((r & (BROWS - 1)) << 18) | c, __float_as_int(v));
    }
}

// ---------------------------------------------------------------------------
// Bucket-local counting sort -> row-sorted CSR (cv, packed 4B) + rowptr.
// ---------------------------------------------------------------------------
__global__ void __launch_bounds__(256)
bucket_sort(const int* __restrict__ bptr,
            const long long* __restrict__ cvtmp,
            unsigned int* __restrict__ cv,
            int* __restrict__ rowptr) {
    __shared__ int2 seg[SEGCAP];     // 36 KB
    __shared__ int cnt[BROWS];
    __shared__ int cur[BROWS];
    const int t = threadIdx.x;
    const int b = blockIdx.x;
    const int beg = bptr[b];
    const int end = bptr[b + 1];
    const int n = end - beg;

    for (int i = t; i < BROWS; i += 256) cnt[i] = 0;
    const bool lds_path = (n <= SEGCAP);

    if (lds_path) {
        for (int j = t; j < n; j += 256) {
            long long e = __builtin_nontemporal_load(&cvtmp[beg + j]);
            seg[j] = make_int2((int)e, (int)(e >> 32));
        }
    }
    __syncthreads();

    if (lds_path) {
        for (int j = t; j < n; j += 256)
            atomicAdd(&cnt[(seg[j].x >> 18) & (BROWS - 1)], 1);
    } else {
        for (int j = beg + t; j < end; j += 256) {
            long long e = cvtmp[j];
            atomicAdd(&cnt[((int)e >> 18) & (BROWS - 1)], 1);
        }
    }
    __syncthreads();

    if (t < 64) {
        int lane = t;
        int v0 = cnt[lane];
        int v1 = cnt[64 + lane];
        int x0 = v0;
        #pragma unroll
        for (int off = 1; off < 64; off <<= 1) {
            int y = __shfl_up(x0, off, 64);
            if (lane >= off) x0 += y;
        }
        int tot0 = __shfl(x0, 63, 64);
        int x1 = v1;
        #pragma unroll
        for (int off = 1; off < 64; off <<= 1) {
            int y = __shfl_up(x1, off, 64);
            if (lane >= off) x1 += y;
        }
        x1 += tot0;
        int e0 = x0 - v0;
        int e1 = x1 - v1;
        cur[lane] = e0;
        cur[64 + lane] = e1;
        int rowbase = b * BROWS;
        if (rowbase + lane < N_NODES)      rowptr[rowbase + lane] = beg + e0;
        if (rowbase + 64 + lane < N_NODES) rowptr[rowbase + 64 + lane] = beg + e1;
    }
    __syncthreads();

    if (lds_path) {
        for (int j = t; j < n; j += 256) {
            int2 e = seg[j];
            int p = atomicAdd(&cur[(e.x >> 18) & (BROWS - 1)], 1);
            float v = __int_as_float(e.y);
            unsigned int qv = (unsigned int)(v * QSCALE + 0.5f);
            if (qv > 16383u) qv = 16383u;
            cv[beg + p] = (qv << 18) | (unsigned int)(e.x & 0x3FFFF);
        }
    } else {
        for (int j = beg + t; j < end; j += 256) {
            long long e = cvtmp[j];
            int lo = (int)e;
            float v = __int_as_float((int)(e >> 32));
            int p = atomicAdd(&cur[(lo >> 18) & (BROWS - 1)], 1);
            unsigned int qv = (unsigned int)(v * QSCALE + 0.5f);
            if (qv > 16383u) qv = 16383u;
            cv[beg + p] = (qv << 18) | (unsigned int)(lo & 0x3FFFF);
        }
    }
}

// ---------------------------------------------------------------------------
// SpMM over CSR, FP16 tables. R6: HALF-WAVE PER ROW — wave = 2 adjacent
// rows (contiguous cv ranges in CSR, so no cv line duplication); each half
// streams its own row's edges contiguously with unroll 16/8/4/1 tiers
// (16 gathers in flight per half for rows >= 16 edges ~ 98% of rows).
// No cross-half reduce. Packed 4-B cv broadcast loads; nt y-store.
// ---------------------------------------------------------------------------
__global__ void spmm_csr(const int* __restrict__ rowptr,
                         const unsigned int* __restrict__ cv,
                         const __half2* __restrict__ x2,
                         __half2* __restrict__ y2) {
    int bucket = blockIdx.x >> 4;
    int sub = blockIdx.x & 15;
    int lane = threadIdx.x & 63;
    int half = lane >> 5;
    int r = bucket * BROWS + sub * 8 + (threadIdx.x >> 6) * 2 + half;
    if (r >= N_NODES) return;
    int d = lane & 31;
    int beg = rowptr[r];
    int end = rowptr[r + 1];
    float ax = 0.0f, ay = 0.0f;
    int j = beg;
    for (; j + 15 < end; j += 16) {     // 16 edges in flight per half
        unsigned int u[16];
        __half2 h[16];
        #pragma unroll
        for (int k = 0; k < 16; ++k) u[k] = cv[j + k];
        #pragma unroll
        for (int k = 0; k < 16; ++k) h[k] = x2[(size_t)(u[k] & 0x3FFFF) * 32 + d];
        #pragma unroll
        for (int k = 0; k < 16; ++k) {
            float2 f = __half22float2(h[k]);
            float v = (float)(u[k] >> 18) * QINV;
            ax = fmaf(v, f.x, ax); ay = fmaf(v, f.y, ay);
        }
    }
    for (; j + 7 < end; j += 8) {
        unsigned int u[8];
        __half2 h[8];
        #pragma unroll
        for (int k = 0; k < 8; ++k) u[k] = cv[j + k];
        #pragma unroll
        for (int k = 0; k < 8; ++k) h[k] = x2[(size_t)(u[k] & 0x3FFFF) * 32 + d];
        #pragma unroll
        for (int k = 0; k < 8; ++k) {
            float2 f = __half22float2(h[k]);
            float v = (float)(u[k] >> 18) * QINV;
            ax = fmaf(v, f.x, ax); ay = fmaf(v, f.y, ay);
        }
    }
    for (; j + 3 < end; j += 4) {
        unsigned int u[4];
        __half2 h[4];
        #pragma unroll
        for (int k = 0; k < 4; ++k) u[k] = cv[j + k];
        #pragma unroll
        for (int k = 0; k < 4; ++k) h[k] = x2[(size_t)(u[k] & 0x3FFFF) * 32 + d];
        #pragma unroll
        for (int k = 0; k < 4; ++k) {
            float2 f = __half22float2(h[k]);
            float v = (float)(u[k] >> 18) * QINV;
            ax = fmaf(v, f.x, ax); ay = fmaf(v, f.y, ay);
        }
    }
    for (; j < end; ++j) {
        unsigned int u = cv[j];
        float2 f = __half22float2(x2[(size_t)(u & 0x3FFFF) * 32 + d]);
        float v = (float)(u >> 18) * QINV;
        ax = fmaf(v, f.x, ax); ay = fmaf(v, f.y, ay);
    }
    __half2 o = __floats2half2_rn(ax, ay);
    unsigned int ob;
    __builtin_memcpy(&ob, &o, 4);
    __builtin_nontemporal_store(ob, (unsigned int*)&y2[(size_t)r * 32 + d]);
}

// ---------------------------------------------------------------------------
// Layer-3 SpMM restricted to batch rows, same half-wave-per-row structure;
// fp32 accumulation straight into ACCB (float2 RMW, 32 lanes per row).
// ---------------------------------------------------------------------------
__global__ void spmm_batch(const int* __restrict__ rowptr,
                           const unsigned int* __restrict__ cv,
                           const __half2* __restrict__ x2,
                           const int* __restrict__ users,
                           const int* __restrict__ items,
                           float* __restrict__ accb) {
    int lane = threadIdx.x & 63;
    int half = lane >> 5;
    int b = blockIdx.x * 8 + (threadIdx.x >> 6) * 2 + half;
    if (b >= 2 * BATCH) return;
    int d = lane & 31;
    int r = (b < BATCH) ? users[b] : (N_USERS + items[b - BATCH]);
    int beg = rowptr[r];
    int end = rowptr[r + 1];
    float ax = 0.0f, ay = 0.0f;
    int j = beg;
    for (; j + 15 < end; j += 16) {
        unsigned int u[16];
        __half2 h[16];
        #pragma unroll
        for (int k = 0; k < 16; ++k) u[k] = cv[j + k];
        #pragma unroll
        for (int k = 0; k < 16; ++k) h[k] = x2[(size_t)(u[k] & 0x3FFFF) * 32 + d];
        #pragma unroll
        for (int k = 0; k < 16; ++k) {
            float2 f = __half22float2(h[k]);
            float v = (float)(u[k] >> 18) * QINV;
            ax = fmaf(v, f.x, ax); ay = fmaf(v, f.y, ay);
        }
    }
    for (; j + 7 < end; j += 8) {
        unsigned int u[8];
        __half2 h[8];
        #pragma unroll
        for (int k = 0; k < 8; ++k) u[k] = cv[j + k];
        #pragma unroll
        for (int k = 0; k < 8; ++k) h[k] = x2[(size_t)(u[k] & 0x3FFFF) * 32 + d];
        #pragma unroll
        for (int k = 0; k < 8; ++k) {
            float2 f = __half22float2(h[k]);
            float v = (float)(u[k] >> 18) * QINV;
            ax = fmaf(v, f.x, ax); ay = fmaf(v, f.y, ay);
        }
    }
    for (; j + 3 < end; j += 4) {
        unsigned int u[4];
        __half2 h[4];
        #pragma unroll
        for (int k = 0; k < 4; ++k) u[k] = cv[j + k];
        #pragma unroll
        for (int k = 0; k < 4; ++k) h[k] = x2[(size_t)(u[k] & 0x3FFFF) * 32 + d];
        #pragma unroll
        for (int k = 0; k < 4; ++k) {
            float2 f = __half22float2(h[k]);
            float v = (float)(u[k] >> 18) * QINV;
            ax = fmaf(v, f.x, ax); ay = fmaf(v, f.y, ay);
        }
    }
    for (; j < end; ++j) {
        unsigned int u = cv[j];
        float2 f = __half22float2(x2[(size_t)(u & 0x3FFFF) * 32 + d]);
        float v = (float)(u >> 18) * QINV;
        ax = fmaf(v, f.x, ax); ay = fmaf(v, f.y, ay);
    }
    float2* a2 = (float2*)(accb + (size_t)b * 64 + 2 * d);
    float2 o = *a2;
    o.x += ax; o.y += ay;
    *a2 = o;
}

// ---------------------------------------------------------------------------
// Batch accumulator add from fp16 node table (layers 1,2).
// ---------------------------------------------------------------------------
__global__ void batch_add(const __half* __restrict__ emb,
                          const int* __restrict__ users,
                          const int* __restrict__ items,
                          float4* __restrict__ accb) {
    int tid = blockIdx.x * blockDim.x + threadIdx.x;
    const int total = 2 * BATCH * (DIM / 4);
    if (tid >= total) return;
    int r = tid >> 4;
    int q = tid & 15;
    int node = (r < BATCH) ? users[r] : (N_USERS + items[r - BATCH]);
    const __half2* e2 = (const __half2*)(emb + (size_t)node * 64 + q * 4);
    float2 lo = __half22float2(e2[0]);
    float2 hi = __half22float2(e2[1]);
    float4 a = accb[tid];
    a.x += lo.x; a.y += lo.y; a.z += hi.x; a.w += hi.y;
    accb[tid] = a;
}

// ---------------------------------------------------------------------------
// Final dot: out[b] = (accb[b] . accb[BATCH+b]) / 16
// ---------------------------------------------------------------------------
__global__ void final_dot(const float* __restrict__ accb,
                          float* __restrict__ out) {
    int b = blockIdx.x * 4 + (threadIdx.x >> 6);
    int lane = threadIdx.x & 63;
    if (b >= BATCH) return;
    float pu = accb[(size_t)b * 64 + lane];
    float pi = accb[(size_t)(BATCH + b) * 64 + lane];
    float p = pu * pi;
    #pragma unroll
    for (int off = 32; off > 0; off >>= 1)
        p += __shfl_down(p, off, 64);
    if (lane == 0) out[b] = p * (1.0f / 16.0f);
}

extern "C" void kernel_launch(void* const* d_in, const int* in_sizes, int n_in,
                              void* d_out, int out_size, void* d_ws, size_t ws_size,
                              hipStream_t stream) {
    const float* uw   = (const float*)d_in[0];
    const float* iw   = (const float*)d_in[1];
    const float* tw   = (const float*)d_in[2];
    const float* vals = (const float*)d_in[3];
    const int*   row  = (const int*)d_in[4];
    const int*   col  = (const int*)d_in[5];
    const int*   users= (const int*)d_in[6];
    const int*   items= (const int*)d_in[7];
    float* out = (float*)d_out;

    // ---- workspace layout (no aliasing; ~96 MB total) ----
    char* ws = (char*)d_ws;
    const size_t NODE_F = (size_t)N_NODES * DIM;       // 9,664,000 elements
    __half* A     = (__half*)ws; ws += NODE_F * 2;     // 19.33 MB
    __half* B     = (__half*)ws; ws += NODE_F * 2;     // 19.33 MB
    float* ACCB   = (float*)ws;  ws += (size_t)2 * BATCH * DIM * 4;
    int*   bcnt   = (int*)ws;    ws += (size_t)NB * 4;
    int*   bptr   = (int*)ws;    ws += (size_t)(NB + 1) * 4;
    int*   rowptr = (int*)ws;    ws += (size_t)(N_NODES + 1) * 4;
    int*   hcnt   = (int*)ws;    ws += (size_t)NPART * NB * 4;   // 1.21 MB
    int*   sync   = (int*)ws;    ws += 64;                       // scanAB counter
    unsigned int* cv = (unsigned int*)ws; ws += (size_t)NNZ * 4; // 16 MB packed
    int2*  cvtmp  = (int2*)ws;   ws += (size_t)NNZ * 8;          // 32 MB

    const int batch_v4 = 2 * BATCH * (DIM / 4);

    // ---- phase0: count + concat + batch_init fused (also zeroes sync) ----
    phase0<<<NPART + CONCAT_BLOCKS + BINIT_BLOCKS, 1024, 0, stream>>>(
        (const float4*)uw, (const float4*)iw, (const float4*)tw, row,
        users, items, (__half2*)A, (float4*)ACCB, hcnt, sync);

    // ---- fused scan + scatter + bucket sort -> CSR ----
    part_scanAB<<<NB / 4, 256, 0, stream>>>(hcnt, bcnt, bptr, rowptr, sync);
    part_scatter<<<NPART, 1024, 0, stream>>>(row, col, vals, hcnt, bptr, cvtmp);
    bucket_sort<<<NB, 256, 0, stream>>>(bptr, (const long long*)cvtmp, cv, rowptr);

    // ---- layers 1,2: full SpMM (fp16 tables); layer 3: batch rows only ----
    const int spmm_blocks = NB * 16;   // 1180 buckets x 16 sub-tiles (8 rows each)
    spmm_csr<<<spmm_blocks, 256, 0, stream>>>(rowptr, cv, (const __half2*)A,
                                              (__half2*)B);
    batch_add<<<(batch_v4 + 255) / 256, 256, 0, stream>>>(
        B, users, items, (float4*)ACCB);
    spmm_csr<<<spmm_blocks, 256, 0, stream>>>(rowptr, cv, (const __half2*)B,
                                              (__half2*)A);
    batch_add<<<(batch_v4 + 255) / 256, 256, 0, stream>>>(
        A, users, items, (float4*)ACCB);
    spmm_batch<<<(2 * BATCH + 7) / 8, 256, 0, stream>>>(
        rowptr, cv, (const __half2*)A, users, items, ACCB);

    final_dot<<<(BATCH + 3) / 4, 256, 0, stream>>>(ACCB, out);
}

// Round 7
// 439.715 us; speedup vs baseline: 1.0149x; 1.0149x over previous
//
#include <hip/hip_runtime.h>
#include <hip/hip_fp16.h>

#define N_USERS 100000
#define N_ITEMS 50000
#define N_TOPICS 1000
#define N_NODES (N_USERS + N_ITEMS + N_TOPICS)   // 151000
#define DIM 64
#define NNZ 4000000
#define BATCH 16384

#define BROWS 128                                 // rows per bucket
#define NB ((N_NODES + BROWS - 1) / BROWS)        // 1180 buckets
#define NPART 128                                 // partition blocks (R7)
#define CHUNK ((NNZ + NPART - 1) / NPART)         // 31250 edges per block
#define SUB 7813                                  // LDS sort sub-chunk
#define SEGCAP 4608                               // LDS seg capacity (36 KB)

// cv entry: (qval14 << 18) | col18 ; val = qval * (1/16384)
#define QSCALE 16384.0f
#define QINV   6.103515625e-05f                   // 1/16384

#define CONCAT_TOTAL (N_NODES * (DIM / 4))        // 2,416,000
#define CONCAT_BLOCKS ((CONCAT_TOTAL + 1023) / 1024)   // 2360
#define BINIT_TOTAL (2 * BATCH * (DIM / 4))       // 524,288
#define BINIT_BLOCKS ((BINIT_TOTAL + 1023) / 1024)     // 512

// ---------------------------------------------------------------------------
// phase0: fused (part_count | concat_init | batch_init) by blockIdx role.
// Also zeroes the scanAB sync counter (re-zeroed on every graph replay).
// ---------------------------------------------------------------------------
__global__ void __launch_bounds__(1024)
phase0(const float4* __restrict__ uw,
       const float4* __restrict__ iw,
       const float4* __restrict__ tw,
       const int* __restrict__ row,
       const int* __restrict__ users,
       const int* __restrict__ items,
       __half2* __restrict__ x0,
       float4* __restrict__ accb,
       int* __restrict__ hcnt,
       int* __restrict__ sync) {
    __shared__ int h[NB];
    const int blk = blockIdx.x;
    const int t = threadIdx.x;
    if (blk < NPART) {
        // ---- part_count role ----
        if (blk == 0 && t == 0) *sync = 0;
        for (int i = t; i < NB; i += 1024) h[i] = 0;
        __syncthreads();
        int e0 = blk * CHUNK;
        int e1 = e0 + CHUNK; if (e1 > NNZ) e1 = NNZ;
        for (int e = e0 + t; e < e1; e += 1024) {
            int r = __builtin_nontemporal_load(&row[e]);
            atomicAdd(&h[r >> 7], 1);
        }
        __syncthreads();
        int* dst = hcnt + (size_t)blk * NB;
        for (int i = t; i < NB; i += 1024) dst[i] = h[i];
    } else if (blk < NPART + CONCAT_BLOCKS) {
        // ---- concat_init role ----
        int tid = (blk - NPART) * 1024 + t;
        if (tid >= CONCAT_TOTAL) return;
        int node = tid >> 4;
        int q = tid & 15;
        float4 v;
        if (node < N_USERS)                v = uw[node * 16 + q];
        else if (node < N_USERS + N_ITEMS) v = iw[(node - N_USERS) * 16 + q];
        else                               v = tw[(node - N_USERS - N_ITEMS) * 16 + q];
        x0[tid * 2]     = __floats2half2_rn(v.x, v.y);
        x0[tid * 2 + 1] = __floats2half2_rn(v.z, v.w);
    } else {
        // ---- batch_init role ----
        int tid = (blk - NPART - CONCAT_BLOCKS) * 1024 + t;
        if (tid >= BINIT_TOTAL) return;
        int r = tid >> 4;
        int q = tid & 15;
        float4 v;
        if (r < BATCH) v = uw[(size_t)users[r] * 16 + q];
        else           v = iw[(size_t)items[r - BATCH] * 16 + q];
        accb[tid] = v;
    }
}

// ---------------------------------------------------------------------------
// Fused scanA + scanB (last-block pattern). 295 blocks x 256 threads.
// ---------------------------------------------------------------------------
__global__ void __launch_bounds__(256)
part_scanAB(int* __restrict__ hcnt,
            int* __restrict__ bcnt,
            int* __restrict__ bptr,
            int* __restrict__ rowptr,
            int* __restrict__ sync) {
    const int t = threadIdx.x;
    const int lane = t & 63;
    const int wid = t >> 6;
    int b = blockIdx.x * 4 + wid;     // grid sized so b < NB always
    int carry = 0;
    for (int base = 0; base < NPART; base += 64) {
        int g = base + lane;
        int v = hcnt[(size_t)g * NB + b];
        int x = v;
        #pragma unroll
        for (int off = 1; off < 64; off <<= 1) {
            int y = __shfl_up(x, off, 64);
            if (lane >= off) x += y;
        }
        int tot = __shfl(x, 63, 64);
        hcnt[(size_t)g * NB + b] = carry + x - v;
        carry += tot;
    }
    if (lane == 0) bcnt[b] = carry;
    __syncthreads();
    __threadfence();
    __shared__ int lastFlag;
    if (t == 0) lastFlag = (atomicAdd(sync, 1) == (int)gridDim.x - 1);
    __syncthreads();
    if (!lastFlag) return;

    // ---- scanB over bcnt[0..NB) with 256 threads ----
    __shared__ int wsum[4];
    __shared__ int carry_s;
    if (t == 0) carry_s = 0;
    __syncthreads();
    for (int base = 0; base < NB; base += 256) {
        int i = base + t;
        int v = (i < NB) ? bcnt[i] : 0;
        int x = v;
        #pragma unroll
        for (int off = 1; off < 64; off <<= 1) {
            int y = __shfl_up(x, off, 64);
            if (lane >= off) x += y;
        }
        if (lane == 63) wsum[wid] = x;
        __syncthreads();
        int wbase = 0;
        for (int w = 0; w < wid; ++w) wbase += wsum[w];
        int excl = carry_s + wbase + (x - v);
        if (i < NB) bptr[i] = excl;
        __syncthreads();
        if (t == 255) carry_s = excl + v;
        __syncthreads();
    }
    if (t == 0) { bptr[NB] = NNZ; rowptr[N_NODES] = NNZ; }
}

// ---------------------------------------------------------------------------
// Partition phase 3 (R7): block-local counting sort -> DENSE writes.
// Each block sorts 7813-edge sub-chunks by bucket in LDS, then writes each
// sorted sub-chunk with consecutive threads -> consecutive addresses, so
// cache lines fill within one instruction window (kills the 3.5x partial-
// line write amplification of the old scattered-in-time pattern).
// LDS: sorted 62.5KB + 3x bucket arrays 14.2KB = ~77KB -> 2 blocks/CU.
// ---------------------------------------------------------------------------
__global__ void __launch_bounds__(1024)
part_scatter(const int* __restrict__ row,
             const int* __restrict__ col,
             const float* __restrict__ vals,
             const int* __restrict__ hcnt,
             const int* __restrict__ bptr,
             int2* __restrict__ cvtmp) {
    __shared__ int2 sorted[SUB];      // 62.5 KB
    __shared__ int cnt_s[NB];
    __shared__ int cur_s[NB];
    __shared__ int gcur[NB];          // running global dst per bucket
    __shared__ int wsum[16];
    __shared__ int carry_s;
    const int g = blockIdx.x;
    const int t = threadIdx.x;
    const int lane = t & 63;
    const int wid = t >> 6;
    const int* hoff = hcnt + (size_t)g * NB;
    for (int i = t; i < NB; i += 1024) gcur[i] = bptr[i] + hoff[i];
    int e0 = g * CHUNK;
    int e1 = e0 + CHUNK; if (e1 > NNZ) e1 = NNZ;

    for (int s0 = e0; s0 < e1; s0 += SUB) {
        int n = e1 - s0; if (n > SUB) n = SUB;
        for (int i = t; i < NB; i += 1024) cnt_s[i] = 0;
        if (t == 0) carry_s = 0;
        __syncthreads();
        // pass A: histogram by bucket
        for (int j = t; j < n; j += 1024) {
            int r = __builtin_nontemporal_load(&row[s0 + j]);
            atomicAdd(&cnt_s[r >> 7], 1);
        }
        __syncthreads();
        // exclusive block-scan cnt_s -> cur_s (local bucket starts)
        for (int base = 0; base < NB; base += 1024) {
            int i = base + t;
            int v = (i < NB) ? cnt_s[i] : 0;
            int x = v;
            #pragma unroll
            for (int off = 1; off < 64; off <<= 1) {
                int y = __shfl_up(x, off, 64);
                if (lane >= off) x += y;
            }
            if (lane == 63) wsum[wid] = x;
            __syncthreads();
            int wbase = 0;
            for (int w = 0; w < wid; ++w) wbase += wsum[w];
            int excl = carry_s + wbase + (x - v);
            if (i < NB) cur_s[i] = excl;
            __syncthreads();
            if (t == 1023) carry_s = excl + v;
            __syncthreads();
        }
        // pass B: scatter into LDS in bucket-sorted order
        for (int j = t; j < n; j += 1024) {
            int r = __builtin_nontemporal_load(&row[s0 + j]);
            int c = __builtin_nontemporal_load(&col[s0 + j]);
            float v = __builtin_nontemporal_load(&vals[s0 + j]);
            int p = atomicAdd(&cur_s[r >> 7], 1);
            sorted[p] = make_int2(((r & (BROWS - 1)) << 18) | c, __float_as_int(v));
        }
        __syncthreads();
        // pass C: dense global write (consecutive j -> consecutive dst per
        // bucket run). After pass B, cur_s[b] == local end of bucket b.
        for (int j = t; j < n; j += 1024) {
            int lo = 0, hi = NB - 1;
            while (lo < hi) {
                int mid = (lo + hi) >> 1;
                if (cur_s[mid] > j) hi = mid; else lo = mid + 1;
            }
            int lb = lo ? cur_s[lo - 1] : 0;
            cvtmp[gcur[lo] + (j - lb)] = sorted[j];
        }
        __syncthreads();
        for (int i = t; i < NB; i += 1024) gcur[i] += cnt_s[i];
        __syncthreads();
    }
}

// ---------------------------------------------------------------------------
// Bucket-local counting sort -> row-sorted CSR (cv, packed 4B) + rowptr.
// ---------------------------------------------------------------------------
__global__ void __launch_bounds__(256)
bucket_sort(const int* __restrict__ bptr,
            const long long* __restrict__ cvtmp,
            unsigned int* __restrict__ cv,
            int* __restrict__ rowptr) {
    __shared__ int2 seg[SEGCAP];     // 36 KB
    __shared__ int cnt[BROWS];
    __shared__ int cur[BROWS];
    const int t = threadIdx.x;
    const int b = blockIdx.x;
    const int beg = bptr[b];
    const int end = bptr[b + 1];
    const int n = end - beg;

    for (int i = t; i < BROWS; i += 256) cnt[i] = 0;
    const bool lds_path = (n <= SEGCAP);

    if (lds_path) {
        for (int j = t; j < n; j += 256) {
            long long e = __builtin_nontemporal_load(&cvtmp[beg + j]);
            seg[j] = make_int2((int)e, (int)(e >> 32));
        }
    }
    __syncthreads();

    if (lds_path) {
        for (int j = t; j < n; j += 256)
            atomicAdd(&cnt[(seg[j].x >> 18) & (BROWS - 1)], 1);
    } else {
        for (int j = beg + t; j < end; j += 256) {
            long long e = cvtmp[j];
            atomicAdd(&cnt[((int)e >> 18) & (BROWS - 1)], 1);
        }
    }
    __syncthreads();

    if (t < 64) {
        int lane = t;
        int v0 = cnt[lane];
        int v1 = cnt[64 + lane];
        int x0 = v0;
        #pragma unroll
        for (int off = 1; off < 64; off <<= 1) {
            int y = __shfl_up(x0, off, 64);
            if (lane >= off) x0 += y;
        }
        int tot0 = __shfl(x0, 63, 64);
        int x1 = v1;
        #pragma unroll
        for (int off = 1; off < 64; off <<= 1) {
            int y = __shfl_up(x1, off, 64);
            if (lane >= off) x1 += y;
        }
        x1 += tot0;
        int e0 = x0 - v0;
        int e1 = x1 - v1;
        cur[lane] = e0;
        cur[64 + lane] = e1;
        int rowbase = b * BROWS;
        if (rowbase + lane < N_NODES)      rowptr[rowbase + lane] = beg + e0;
        if (rowbase + 64 + lane < N_NODES) rowptr[rowbase + 64 + lane] = beg + e1;
    }
    __syncthreads();

    if (lds_path) {
        for (int j = t; j < n; j += 256) {
            int2 e = seg[j];
            int p = atomicAdd(&cur[(e.x >> 18) & (BROWS - 1)], 1);
            float v = __int_as_float(e.y);
            unsigned int qv = (unsigned int)(v * QSCALE + 0.5f);
            if (qv > 16383u) qv = 16383u;
            cv[beg + p] = (qv << 18) | (unsigned int)(e.x & 0x3FFFF);
        }
    } else {
        for (int j = beg + t; j < end; j += 256) {
            long long e = cvtmp[j];
            int lo = (int)e;
            float v = __int_as_float((int)(e >> 32));
            int p = atomicAdd(&cur[(lo >> 18) & (BROWS - 1)], 1);
            unsigned int qv = (unsigned int)(v * QSCALE + 0.5f);
            if (qv > 16383u) qv = 16383u;
            cv[beg + p] = (qv << 18) | (unsigned int)(lo & 0x3FFFF);
        }
    }
}

// ---------------------------------------------------------------------------
// SpMM over CSR, FP16 tables. HALF-WAVE PER ROW — wave = 2 adjacent rows
// (contiguous cv ranges, no cv line duplication); unroll 16/8/4/1 tiers.
// Packed 4-B cv broadcast loads; nt y-store.
// ---------------------------------------------------------------------------
__global__ void spmm_csr(const int* __restrict__ rowptr,
                         const unsigned int* __restrict__ cv,
                         const __half2* __restrict__ x2,
                         __half2* __restrict__ y2) {
    int bucket = blockIdx.x >> 4;
    int sub = blockIdx.x & 15;
    int lane = threadIdx.x & 63;
    int half = lane >> 5;
    int r = bucket * BROWS + sub * 8 + (threadIdx.x >> 6) * 2 + half;
    if (r >= N_NODES) return;
    int d = lane & 31;
    int beg = rowptr[r];
    int end = rowptr[r + 1];
    float ax = 0.0f, ay = 0.0f;
    int j = beg;
    for (; j + 15 < end; j += 16) {     // 16 edges in flight per half
        unsigned int u[16];
        __half2 h[16];
        #pragma unroll
        for (int k = 0; k < 16; ++k) u[k] = cv[j + k];
        #pragma unroll
        for (int k = 0; k < 16; ++k) h[k] = x2[(size_t)(u[k] & 0x3FFFF) * 32 + d];
        #pragma unroll
        for (int k = 0; k < 16; ++k) {
            float2 f = __half22float2(h[k]);
            float v = (float)(u[k] >> 18) * QINV;
            ax = fmaf(v, f.x, ax); ay = fmaf(v, f.y, ay);
        }
    }
    for (; j + 7 < end; j += 8) {
        unsigned int u[8];
        __half2 h[8];
        #pragma unroll
        for (int k = 0; k < 8; ++k) u[k] = cv[j + k];
        #pragma unroll
        for (int k = 0; k < 8; ++k) h[k] = x2[(size_t)(u[k] & 0x3FFFF) * 32 + d];
        #pragma unroll
        for (int k = 0; k < 8; ++k) {
            float2 f = __half22float2(h[k]);
            float v = (float)(u[k] >> 18) * QINV;
            ax = fmaf(v, f.x, ax); ay = fmaf(v, f.y, ay);
        }
    }
    for (; j + 3 < end; j += 4) {
        unsigned int u[4];
        __half2 h[4];
        #pragma unroll
        for (int k = 0; k < 4; ++k) u[k] = cv[j + k];
        #pragma unroll
        for (int k = 0; k < 4; ++k) h[k] = x2[(size_t)(u[k] & 0x3FFFF) * 32 + d];
        #pragma unroll
        for (int k = 0; k < 4; ++k) {
            float2 f = __half22float2(h[k]);
            float v = (float)(u[k] >> 18) * QINV;
            ax = fmaf(v, f.x, ax); ay = fmaf(v, f.y, ay);
        }
    }
    for (; j < end; ++j) {
        unsigned int u = cv[j];
        float2 f = __half22float2(x2[(size_t)(u & 0x3FFFF) * 32 + d]);
        float v = (float)(u >> 18) * QINV;
        ax = fmaf(v, f.x, ax); ay = fmaf(v, f.y, ay);
    }
    __half2 o = __floats2half2_rn(ax, ay);
    unsigned int ob;
    __builtin_memcpy(&ob, &o, 4);
    __builtin_nontemporal_store(ob, (unsigned int*)&y2[(size_t)r * 32 + d]);
}

// ---------------------------------------------------------------------------
// Layer-3 SpMM restricted to batch rows, same half-wave-per-row structure;
// fp32 accumulation straight into ACCB (float2 RMW, 32 lanes per row).
// ---------------------------------------------------------------------------
__global__ void spmm_batch(const int* __restrict__ rowptr,
                           const unsigned int* __restrict__ cv,
                           const __half2* __restrict__ x2,
                           const int* __restrict__ users,
                           const int* __restrict__ items,
                           float* __restrict__ accb) {
    int lane = threadIdx.x & 63;
    int half = lane >> 5;
    int b = blockIdx.x * 8 + (threadIdx.x >> 6) * 2 + half;
    if (b >= 2 * BATCH) return;
    int d = lane & 31;
    int r = (b < BATCH) ? users[b] : (N_USERS + items[b - BATCH]);
    int beg = rowptr[r];
    int end = rowptr[r + 1];
    float ax = 0.0f, ay = 0.0f;
    int j = beg;
    for (; j + 15 < end; j += 16) {
        unsigned int u[16];
        __half2 h[16];
        #pragma unroll
        for (int k = 0; k < 16; ++k) u[k] = cv[j + k];
        #pragma unroll
        for (int k = 0; k < 16; ++k) h[k] = x2[(size_t)(u[k] & 0x3FFFF) * 32 + d];
        #pragma unroll
        for (int k = 0; k < 16; ++k) {
            float2 f = __half22float2(h[k]);
            float v = (float)(u[k] >> 18) * QINV;
            ax = fmaf(v, f.x, ax); ay = fmaf(v, f.y, ay);
        }
    }
    for (; j + 7 < end; j += 8) {
        unsigned int u[8];
        __half2 h[8];
        #pragma unroll
        for (int k = 0; k < 8; ++k) u[k] = cv[j + k];
        #pragma unroll
        for (int k = 0; k < 8; ++k) h[k] = x2[(size_t)(u[k] & 0x3FFFF) * 32 + d];
        #pragma unroll
        for (int k = 0; k < 8; ++k) {
            float2 f = __half22float2(h[k]);
            float v = (float)(u[k] >> 18) * QINV;
            ax = fmaf(v, f.x, ax); ay = fmaf(v, f.y, ay);
        }
    }
    for (; j + 3 < end; j += 4) {
        unsigned int u[4];
        __half2 h[4];
        #pragma unroll
        for (int k = 0; k < 4; ++k) u[k] = cv[j + k];
        #pragma unroll
        for (int k = 0; k < 4; ++k) h[k] = x2[(size_t)(u[k] & 0x3FFFF) * 32 + d];
        #pragma unroll
        for (int k = 0; k < 4; ++k) {
            float2 f = __half22float2(h[k]);
            float v = (float)(u[k] >> 18) * QINV;
            ax = fmaf(v, f.x, ax); ay = fmaf(v, f.y, ay);
        }
    }
    for (; j < end; ++j) {
        unsigned int u = cv[j];
        float2 f = __half22float2(x2[(size_t)(u & 0x3FFFF) * 32 + d]);
        float v = (float)(u >> 18) * QINV;
        ax = fmaf(v, f.x, ax); ay = fmaf(v, f.y, ay);
    }
    float2* a2 = (float2*)(accb + (size_t)b * 64 + 2 * d);
    float2 o = *a2;
    o.x += ax; o.y += ay;
    *a2 = o;
}

// ---------------------------------------------------------------------------
// Batch accumulator add from fp16 node table (layers 1,2).
// ---------------------------------------------------------------------------
__global__ void batch_add(const __half* __restrict__ emb,
                          const int* __restrict__ users,
                          const int* __restrict__ items,
                          float4* __restrict__ accb) {
    int tid = blockIdx.x * blockDim.x + threadIdx.x;
    const int total = 2 * BATCH * (DIM / 4);
    if (tid >= total) return;
    int r = tid >> 4;
    int q = tid & 15;
    int node = (r < BATCH) ? users[r] : (N_USERS + items[r - BATCH]);
    const __half2* e2 = (const __half2*)(emb + (size_t)node * 64 + q * 4);
    float2 lo = __half22float2(e2[0]);
    float2 hi = __half22float2(e2[1]);
    float4 a = accb[tid];
    a.x += lo.x; a.y += lo.y; a.z += hi.x; a.w += hi.y;
    accb[tid] = a;
}

// ---------------------------------------------------------------------------
// Final dot: out[b] = (accb[b] . accb[BATCH+b]) / 16
// ---------------------------------------------------------------------------
__global__ void final_dot(const float* __restrict__ accb,
                          float* __restrict__ out) {
    int b = blockIdx.x * 4 + (threadIdx.x >> 6);
    int lane = threadIdx.x & 63;
    if (b >= BATCH) return;
    float pu = accb[(size_t)b * 64 + lane];
    float pi = accb[(size_t)(BATCH + b) * 64 + lane];
    float p = pu * pi;
    #pragma unroll
    for (int off = 32; off > 0; off >>= 1)
        p += __shfl_down(p, off, 64);
    if (lane == 0) out[b] = p * (1.0f / 16.0f);
}

extern "C" void kernel_launch(void* const* d_in, const int* in_sizes, int n_in,
                              void* d_out, int out_size, void* d_ws, size_t ws_size,
                              hipStream_t stream) {
    const float* uw   = (const float*)d_in[0];
    const float* iw   = (const float*)d_in[1];
    const float* tw   = (const float*)d_in[2];
    const float* vals = (const float*)d_in[3];
    const int*   row  = (const int*)d_in[4];
    const int*   col  = (const int*)d_in[5];
    const int*   users= (const int*)d_in[6];
    const int*   items= (const int*)d_in[7];
    float* out = (float*)d_out;

    // ---- workspace layout (no aliasing; ~96 MB total) ----
    char* ws = (char*)d_ws;
    const size_t NODE_F = (size_t)N_NODES * DIM;       // 9,664,000 elements
    __half* A     = (__half*)ws; ws += NODE_F * 2;     // 19.33 MB
    __half* B     = (__half*)ws; ws += NODE_F * 2;     // 19.33 MB
    float* ACCB   = (float*)ws;  ws += (size_t)2 * BATCH * DIM * 4;
    int*   bcnt   = (int*)ws;    ws += (size_t)NB * 4;
    int*   bptr   = (int*)ws;    ws += (size_t)(NB + 1) * 4;
    int*   rowptr = (int*)ws;    ws += (size_t)(N_NODES + 1) * 4;
    int*   hcnt   = (int*)ws;    ws += (size_t)NPART * NB * 4;   // 604 KB
    int*   sync   = (int*)ws;    ws += 64;                       // scanAB counter
    unsigned int* cv = (unsigned int*)ws; ws += (size_t)NNZ * 4; // 16 MB packed
    int2*  cvtmp  = (int2*)ws;   ws += (size_t)NNZ * 8;          // 32 MB

    const int batch_v4 = 2 * BATCH * (DIM / 4);

    // ---- phase0: count + concat + batch_init fused (also zeroes sync) ----
    phase0<<<NPART + CONCAT_BLOCKS + BINIT_BLOCKS, 1024, 0, stream>>>(
        (const float4*)uw, (const float4*)iw, (const float4*)tw, row,
        users, items, (__half2*)A, (float4*)ACCB, hcnt, sync);

    // ---- fused scan + LDS-sorted scatter + bucket sort -> CSR ----
    part_scanAB<<<NB / 4, 256, 0, stream>>>(hcnt, bcnt, bptr, rowptr, sync);
    part_scatter<<<NPART, 1024, 0, stream>>>(row, col, vals, hcnt, bptr, cvtmp);
    bucket_sort<<<NB, 256, 0, stream>>>(bptr, (const long long*)cvtmp, cv, rowptr);

    // ---- layers 1,2: full SpMM (fp16 tables); layer 3: batch rows only ----
    const int spmm_blocks = NB * 16;   // 1180 buckets x 16 sub-tiles (8 rows each)
    spmm_csr<<<spmm_blocks, 256, 0, stream>>>(rowptr, cv, (const __half2*)A,
                                              (__half2*)B);
    batch_add<<<(batch_v4 + 255) / 256, 256, 0, stream>>>(
        B, users, items, (float4*)ACCB);
    spmm_csr<<<spmm_blocks, 256, 0, stream>>>(rowptr, cv, (const __half2*)B,
                                              (__half2*)A);
    batch_add<<<(batch_v4 + 255) / 256, 256, 0, stream>>>(
        A, users, items, (float4*)ACCB);
    spmm_batch<<<(2 * BATCH + 7) / 8, 256, 0, stream>>>(
        rowptr, cv, (const __half2*)A, users, items, ACCB);

    final_dot<<<(BATCH + 3) / 4, 256, 0, stream>>>(ACCB, out);
}

// Round 8
// 408.873 us; speedup vs baseline: 1.0915x; 1.0754x over previous
//
#include <hip/hip_runtime.h>
#include <hip/hip_fp16.h>

#define N_USERS 100000
#define N_ITEMS 50000
#define N_TOPICS 1000
#define N_NODES (N_USERS + N_ITEMS + N_TOPICS)   // 151000
#define DIM 64
#define NNZ 4000000
#define BATCH 16384

#define BROWS 128                                 // rows per bucket
#define NB ((N_NODES + BROWS - 1) / BROWS)        // 1180 buckets
#define NPART 256                                 // partition blocks (R8: full CU coverage)
#define CHUNK ((NNZ + NPART - 1) / NPART)         // 15625 edges per block
#define SUB 7813                                  // LDS sort sub-chunk
#define SEGCAP 4608                               // LDS seg capacity (36 KB)

// cv entry: (qval14 << 18) | col18 ; val = qval * (1/16384)
#define QSCALE 16384.0f
#define QINV   6.103515625e-05f                   // 1/16384

#define CONCAT_TOTAL (N_NODES * (DIM / 4))        // 2,416,000
#define CONCAT_BLOCKS ((CONCAT_TOTAL + 1023) / 1024)   // 2360
#define BINIT_TOTAL (2 * BATCH * (DIM / 4))       // 524,288
#define BINIT_BLOCKS ((BINIT_TOTAL + 1023) / 1024)     // 512

// ---------------------------------------------------------------------------
// phase0: fused (part_count | concat_init | batch_init) by blockIdx role.
// Also zeroes the scanAB sync counter (re-zeroed on every graph replay).
// ---------------------------------------------------------------------------
__global__ void __launch_bounds__(1024)
phase0(const float4* __restrict__ uw,
       const float4* __restrict__ iw,
       const float4* __restrict__ tw,
       const int* __restrict__ row,
       const int* __restrict__ users,
       const int* __restrict__ items,
       __half2* __restrict__ x0,
       float4* __restrict__ accb,
       int* __restrict__ hcnt,
       int* __restrict__ sync) {
    __shared__ int h[NB];
    const int blk = blockIdx.x;
    const int t = threadIdx.x;
    if (blk < NPART) {
        // ---- part_count role ----
        if (blk == 0 && t == 0) *sync = 0;
        for (int i = t; i < NB; i += 1024) h[i] = 0;
        __syncthreads();
        int e0 = blk * CHUNK;
        int e1 = e0 + CHUNK; if (e1 > NNZ) e1 = NNZ;
        for (int e = e0 + t; e < e1; e += 1024) {
            int r = __builtin_nontemporal_load(&row[e]);
            atomicAdd(&h[r >> 7], 1);
        }
        __syncthreads();
        int* dst = hcnt + (size_t)blk * NB;
        for (int i = t; i < NB; i += 1024) dst[i] = h[i];
    } else if (blk < NPART + CONCAT_BLOCKS) {
        // ---- concat_init role ----
        int tid = (blk - NPART) * 1024 + t;
        if (tid >= CONCAT_TOTAL) return;
        int node = tid >> 4;
        int q = tid & 15;
        float4 v;
        if (node < N_USERS)                v = uw[node * 16 + q];
        else if (node < N_USERS + N_ITEMS) v = iw[(node - N_USERS) * 16 + q];
        else                               v = tw[(node - N_USERS - N_ITEMS) * 16 + q];
        x0[tid * 2]     = __floats2half2_rn(v.x, v.y);
        x0[tid * 2 + 1] = __floats2half2_rn(v.z, v.w);
    } else {
        // ---- batch_init role ----
        int tid = (blk - NPART - CONCAT_BLOCKS) * 1024 + t;
        if (tid >= BINIT_TOTAL) return;
        int r = tid >> 4;
        int q = tid & 15;
        float4 v;
        if (r < BATCH) v = uw[(size_t)users[r] * 16 + q];
        else           v = iw[(size_t)items[r - BATCH] * 16 + q];
        accb[tid] = v;
    }
}

// ---------------------------------------------------------------------------
// Fused scanA + scanB (last-block pattern). 295 blocks x 256 threads.
// ---------------------------------------------------------------------------
__global__ void __launch_bounds__(256)
part_scanAB(int* __restrict__ hcnt,
            int* __restrict__ bcnt,
            int* __restrict__ bptr,
            int* __restrict__ rowptr,
            int* __restrict__ sync) {
    const int t = threadIdx.x;
    const int lane = t & 63;
    const int wid = t >> 6;
    int b = blockIdx.x * 4 + wid;     // grid sized so b < NB always
    int carry = 0;
    for (int base = 0; base < NPART; base += 64) {
        int g = base + lane;
        int v = hcnt[(size_t)g * NB + b];
        int x = v;
        #pragma unroll
        for (int off = 1; off < 64; off <<= 1) {
            int y = __shfl_up(x, off, 64);
            if (lane >= off) x += y;
        }
        int tot = __shfl(x, 63, 64);
        hcnt[(size_t)g * NB + b] = carry + x - v;
        carry += tot;
    }
    if (lane == 0) bcnt[b] = carry;
    __syncthreads();
    __threadfence();
    __shared__ int lastFlag;
    if (t == 0) lastFlag = (atomicAdd(sync, 1) == (int)gridDim.x - 1);
    __syncthreads();
    if (!lastFlag) return;

    // ---- scanB over bcnt[0..NB) with 256 threads ----
    __shared__ int wsum[4];
    __shared__ int carry_s;
    if (t == 0) carry_s = 0;
    __syncthreads();
    for (int base = 0; base < NB; base += 256) {
        int i = base + t;
        int v = (i < NB) ? bcnt[i] : 0;
        int x = v;
        #pragma unroll
        for (int off = 1; off < 64; off <<= 1) {
            int y = __shfl_up(x, off, 64);
            if (lane >= off) x += y;
        }
        if (lane == 63) wsum[wid] = x;
        __syncthreads();
        int wbase = 0;
        for (int w = 0; w < wid; ++w) wbase += wsum[w];
        int excl = carry_s + wbase + (x - v);
        if (i < NB) bptr[i] = excl;
        __syncthreads();
        if (t == 255) carry_s = excl + v;
        __syncthreads();
    }
    if (t == 0) { bptr[NB] = NNZ; rowptr[N_NODES] = NNZ; }
}

// ---------------------------------------------------------------------------
// Partition phase 3: block-local counting sort -> DENSE writes.
// R8: NPART=256 (one block per CU, was 128 = half the chip idle) and
// pass B records each element's bucket (bktSorted) so pass C does 3 LDS
// lookups instead of an 11-step divergent binary search.
// LDS: sorted 62.5K + bktSorted 15.6K + 3xNB arrays 14.2K ~= 92.4 KB.
// ---------------------------------------------------------------------------
__global__ void __launch_bounds__(1024)
part_scatter(const int* __restrict__ row,
             const int* __restrict__ col,
             const float* __restrict__ vals,
             const int* __restrict__ hcnt,
             const int* __restrict__ bptr,
             int2* __restrict__ cvtmp) {
    __shared__ int2 sorted[SUB];           // 62.5 KB
    __shared__ unsigned short bktSorted[SUB];  // 15.6 KB
    __shared__ int cnt_s[NB];
    __shared__ int cur_s[NB];
    __shared__ int gcur[NB];               // running global dst per bucket
    __shared__ int wsum[16];
    __shared__ int carry_s;
    const int g = blockIdx.x;
    const int t = threadIdx.x;
    const int lane = t & 63;
    const int wid = t >> 6;
    const int* hoff = hcnt + (size_t)g * NB;
    for (int i = t; i < NB; i += 1024) gcur[i] = bptr[i] + hoff[i];
    int e0 = g * CHUNK;
    int e1 = e0 + CHUNK; if (e1 > NNZ) e1 = NNZ;

    for (int s0 = e0; s0 < e1; s0 += SUB) {
        int n = e1 - s0; if (n > SUB) n = SUB;
        for (int i = t; i < NB; i += 1024) cnt_s[i] = 0;
        if (t == 0) carry_s = 0;
        __syncthreads();
        // pass A: histogram by bucket
        for (int j = t; j < n; j += 1024) {
            int r = __builtin_nontemporal_load(&row[s0 + j]);
            atomicAdd(&cnt_s[r >> 7], 1);
        }
        __syncthreads();
        // exclusive block-scan cnt_s -> cur_s (local bucket starts)
        for (int base = 0; base < NB; base += 1024) {
            int i = base + t;
            int v = (i < NB) ? cnt_s[i] : 0;
            int x = v;
            #pragma unroll
            for (int off = 1; off < 64; off <<= 1) {
                int y = __shfl_up(x, off, 64);
                if (lane >= off) x += y;
            }
            if (lane == 63) wsum[wid] = x;
            __syncthreads();
            int wbase = 0;
            for (int w = 0; w < wid; ++w) wbase += wsum[w];
            int excl = carry_s + wbase + (x - v);
            if (i < NB) cur_s[i] = excl;
            __syncthreads();
            if (t == 1023) carry_s = excl + v;
            __syncthreads();
        }
        // pass B: scatter into LDS in bucket-sorted order; record bucket
        for (int j = t; j < n; j += 1024) {
            int r = __builtin_nontemporal_load(&row[s0 + j]);
            int c = __builtin_nontemporal_load(&col[s0 + j]);
            float v = __builtin_nontemporal_load(&vals[s0 + j]);
            int b = r >> 7;
            int p = atomicAdd(&cur_s[b], 1);
            sorted[p] = make_int2(((r & (BROWS - 1)) << 18) | c, __float_as_int(v));
            bktSorted[p] = (unsigned short)b;
        }
        __syncthreads();
        // pass C: dense global write. After pass B, cur_s[b] == local END of
        // bucket b; local start = cur_s[b] - cnt_s[b].
        for (int j = t; j < n; j += 1024) {
            int b = bktSorted[j];
            int lb = cur_s[b] - cnt_s[b];
            cvtmp[gcur[b] + (j - lb)] = sorted[j];
        }
        __syncthreads();
        for (int i = t; i < NB; i += 1024) gcur[i] += cnt_s[i];
        __syncthreads();
    }
}

// ---------------------------------------------------------------------------
// Bucket-local counting sort -> row-sorted CSR (cv, packed 4B) + rowptr.
// ---------------------------------------------------------------------------
__global__ void __launch_bounds__(256)
bucket_sort(const int* __restrict__ bptr,
            const long long* __restrict__ cvtmp,
            unsigned int* __restrict__ cv,
            int* __restrict__ rowptr) {
    __shared__ int2 seg[SEGCAP];     // 36 KB
    __shared__ int cnt[BROWS];
    __shared__ int cur[BROWS];
    const int t = threadIdx.x;
    const int b = blockIdx.x;
    const int beg = bptr[b];
    const int end = bptr[b + 1];
    const int n = end - beg;

    for (int i = t; i < BROWS; i += 256) cnt[i] = 0;
    const bool lds_path = (n <= SEGCAP);

    if (lds_path) {
        for (int j = t; j < n; j += 256) {
            long long e = __builtin_nontemporal_load(&cvtmp[beg + j]);
            seg[j] = make_int2((int)e, (int)(e >> 32));
        }
    }
    __syncthreads();

    if (lds_path) {
        for (int j = t; j < n; j += 256)
            atomicAdd(&cnt[(seg[j].x >> 18) & (BROWS - 1)], 1);
    } else {
        for (int j = beg + t; j < end; j += 256) {
            long long e = cvtmp[j];
            atomicAdd(&cnt[((int)e >> 18) & (BROWS - 1)], 1);
        }
    }
    __syncthreads();

    if (t < 64) {
        int lane = t;
        int v0 = cnt[lane];
        int v1 = cnt[64 + lane];
        int x0 = v0;
        #pragma unroll
        for (int off = 1; off < 64; off <<= 1) {
            int y = __shfl_up(x0, off, 64);
            if (lane >= off) x0 += y;
        }
        int tot0 = __shfl(x0, 63, 64);
        int x1 = v1;
        #pragma unroll
        for (int off = 1; off < 64; off <<= 1) {
            int y = __shfl_up(x1, off, 64);
            if (lane >= off) x1 += y;
        }
        x1 += tot0;
        int e0 = x0 - v0;
        int e1 = x1 - v1;
        cur[lane] = e0;
        cur[64 + lane] = e1;
        int rowbase = b * BROWS;
        if (rowbase + lane < N_NODES)      rowptr[rowbase + lane] = beg + e0;
        if (rowbase + 64 + lane < N_NODES) rowptr[rowbase + 64 + lane] = beg + e1;
    }
    __syncthreads();

    if (lds_path) {
        for (int j = t; j < n; j += 256) {
            int2 e = seg[j];
            int p = atomicAdd(&cur[(e.x >> 18) & (BROWS - 1)], 1);
            float v = __int_as_float(e.y);
            unsigned int qv = (unsigned int)(v * QSCALE + 0.5f);
            if (qv > 16383u) qv = 16383u;
            cv[beg + p] = (qv << 18) | (unsigned int)(e.x & 0x3FFFF);
        }
    } else {
        for (int j = beg + t; j < end; j += 256) {
            long long e = cvtmp[j];
            int lo = (int)e;
            float v = __int_as_float((int)(e >> 32));
            int p = atomicAdd(&cur[(lo >> 18) & (BROWS - 1)], 1);
            unsigned int qv = (unsigned int)(v * QSCALE + 0.5f);
            if (qv > 16383u) qv = 16383u;
            cv[beg + p] = (qv << 18) | (unsigned int)(lo & 0x3FFFF);
        }
    }
}

// ---------------------------------------------------------------------------
// SpMM over CSR, FP16 tables. HALF-WAVE PER ROW — wave = 2 adjacent rows
// (contiguous cv ranges, no cv line duplication); unroll 16/8/4/1 tiers.
// Packed 4-B cv broadcast loads; nt y-store.
// ---------------------------------------------------------------------------
__global__ void spmm_csr(const int* __restrict__ rowptr,
                         const unsigned int* __restrict__ cv,
                         const __half2* __restrict__ x2,
                         __half2* __restrict__ y2) {
    int bucket = blockIdx.x >> 4;
    int sub = blockIdx.x & 15;
    int lane = threadIdx.x & 63;
    int half = lane >> 5;
    int r = bucket * BROWS + sub * 8 + (threadIdx.x >> 6) * 2 + half;
    if (r >= N_NODES) return;
    int d = lane & 31;
    int beg = rowptr[r];
    int end = rowptr[r + 1];
    float ax = 0.0f, ay = 0.0f;
    int j = beg;
    for (; j + 15 < end; j += 16) {     // 16 edges in flight per half
        unsigned int u[16];
        __half2 h[16];
        #pragma unroll
        for (int k = 0; k < 16; ++k) u[k] = cv[j + k];
        #pragma unroll
        for (int k = 0; k < 16; ++k) h[k] = x2[(size_t)(u[k] & 0x3FFFF) * 32 + d];
        #pragma unroll
        for (int k = 0; k < 16; ++k) {
            float2 f = __half22float2(h[k]);
            float v = (float)(u[k] >> 18) * QINV;
            ax = fmaf(v, f.x, ax); ay = fmaf(v, f.y, ay);
        }
    }
    for (; j + 7 < end; j += 8) {
        unsigned int u[8];
        __half2 h[8];
        #pragma unroll
        for (int k = 0; k < 8; ++k) u[k] = cv[j + k];
        #pragma unroll
        for (int k = 0; k < 8; ++k) h[k] = x2[(size_t)(u[k] & 0x3FFFF) * 32 + d];
        #pragma unroll
        for (int k = 0; k < 8; ++k) {
            float2 f = __half22float2(h[k]);
            float v = (float)(u[k] >> 18) * QINV;
            ax = fmaf(v, f.x, ax); ay = fmaf(v, f.y, ay);
        }
    }
    for (; j + 3 < end; j += 4) {
        unsigned int u[4];
        __half2 h[4];
        #pragma unroll
        for (int k = 0; k < 4; ++k) u[k] = cv[j + k];
        #pragma unroll
        for (int k = 0; k < 4; ++k) h[k] = x2[(size_t)(u[k] & 0x3FFFF) * 32 + d];
        #pragma unroll
        for (int k = 0; k < 4; ++k) {
            float2 f = __half22float2(h[k]);
            float v = (float)(u[k] >> 18) * QINV;
            ax = fmaf(v, f.x, ax); ay = fmaf(v, f.y, ay);
        }
    }
    for (; j < end; ++j) {
        unsigned int u = cv[j];
        float2 f = __half22float2(x2[(size_t)(u & 0x3FFFF) * 32 + d]);
        float v = (float)(u >> 18) * QINV;
        ax = fmaf(v, f.x, ax); ay = fmaf(v, f.y, ay);
    }
    __half2 o = __floats2half2_rn(ax, ay);
    unsigned int ob;
    __builtin_memcpy(&ob, &o, 4);
    __builtin_nontemporal_store(ob, (unsigned int*)&y2[(size_t)r * 32 + d]);
}

// ---------------------------------------------------------------------------
// Layer-3 SpMM restricted to batch rows, same half-wave-per-row structure;
// fp32 accumulation straight into ACCB (float2 RMW, 32 lanes per row).
// ---------------------------------------------------------------------------
__global__ void spmm_batch(const int* __restrict__ rowptr,
                           const unsigned int* __restrict__ cv,
                           const __half2* __restrict__ x2,
                           const int* __restrict__ users,
                           const int* __restrict__ items,
                           float* __restrict__ accb) {
    int lane = threadIdx.x & 63;
    int half = lane >> 5;
    int b = blockIdx.x * 8 + (threadIdx.x >> 6) * 2 + half;
    if (b >= 2 * BATCH) return;
    int d = lane & 31;
    int r = (b < BATCH) ? users[b] : (N_USERS + items[b - BATCH]);
    int beg = rowptr[r];
    int end = rowptr[r + 1];
    float ax = 0.0f, ay = 0.0f;
    int j = beg;
    for (; j + 15 < end; j += 16) {
        unsigned int u[16];
        __half2 h[16];
        #pragma unroll
        for (int k = 0; k < 16; ++k) u[k] = cv[j + k];
        #pragma unroll
        for (int k = 0; k < 16; ++k) h[k] = x2[(size_t)(u[k] & 0x3FFFF) * 32 + d];
        #pragma unroll
        for (int k = 0; k < 16; ++k) {
            float2 f = __half22float2(h[k]);
            float v = (float)(u[k] >> 18) * QINV;
            ax = fmaf(v, f.x, ax); ay = fmaf(v, f.y, ay);
        }
    }
    for (; j + 7 < end; j += 8) {
        unsigned int u[8];
        __half2 h[8];
        #pragma unroll
        for (int k = 0; k < 8; ++k) u[k] = cv[j + k];
        #pragma unroll
        for (int k = 0; k < 8; ++k) h[k] = x2[(size_t)(u[k] & 0x3FFFF) * 32 + d];
        #pragma unroll
        for (int k = 0; k < 8; ++k) {
            float2 f = __half22float2(h[k]);
            float v = (float)(u[k] >> 18) * QINV;
            ax = fmaf(v, f.x, ax); ay = fmaf(v, f.y, ay);
        }
    }
    for (; j + 3 < end; j += 4) {
        unsigned int u[4];
        __half2 h[4];
        #pragma unroll
        for (int k = 0; k < 4; ++k) u[k] = cv[j + k];
        #pragma unroll
        for (int k = 0; k < 4; ++k) h[k] = x2[(size_t)(u[k] & 0x3FFFF) * 32 + d];
        #pragma unroll
        for (int k = 0; k < 4; ++k) {
            float2 f = __half22float2(h[k]);
            float v = (float)(u[k] >> 18) * QINV;
            ax = fmaf(v, f.x, ax); ay = fmaf(v, f.y, ay);
        }
    }
    for (; j < end; ++j) {
        unsigned int u = cv[j];
        float2 f = __half22float2(x2[(size_t)(u & 0x3FFFF) * 32 + d]);
        float v = (float)(u >> 18) * QINV;
        ax = fmaf(v, f.x, ax); ay = fmaf(v, f.y, ay);
    }
    float2* a2 = (float2*)(accb + (size_t)b * 64 + 2 * d);
    float2 o = *a2;
    o.x += ax; o.y += ay;
    *a2 = o;
}

// ---------------------------------------------------------------------------
// Batch accumulator add from fp16 node table (layers 1,2).
// ---------------------------------------------------------------------------
__global__ void batch_add(const __half* __restrict__ emb,
                          const int* __restrict__ users,
                          const int* __restrict__ items,
                          float4* __restrict__ accb) {
    int tid = blockIdx.x * blockDim.x + threadIdx.x;
    const int total = 2 * BATCH * (DIM / 4);
    if (tid >= total) return;
    int r = tid >> 4;
    int q = tid & 15;
    int node = (r < BATCH) ? users[r] : (N_USERS + items[r - BATCH]);
    const __half2* e2 = (const __half2*)(emb + (size_t)node * 64 + q * 4);
    float2 lo = __half22float2(e2[0]);
    float2 hi = __half22float2(e2[1]);
    float4 a = accb[tid];
    a.x += lo.x; a.y += lo.y; a.z += hi.x; a.w += hi.y;
    accb[tid] = a;
}

// ---------------------------------------------------------------------------
// Final dot: out[b] = (accb[b] . accb[BATCH+b]) / 16
// ---------------------------------------------------------------------------
__global__ void final_dot(const float* __restrict__ accb,
                          float* __restrict__ out) {
    int b = blockIdx.x * 4 + (threadIdx.x >> 6);
    int lane = threadIdx.x & 63;
    if (b >= BATCH) return;
    float pu = accb[(size_t)b * 64 + lane];
    float pi = accb[(size_t)(BATCH + b) * 64 + lane];
    float p = pu * pi;
    #pragma unroll
    for (int off = 32; off > 0; off >>= 1)
        p += __shfl_down(p, off, 64);
    if (lane == 0) out[b] = p * (1.0f / 16.0f);
}

extern "C" void kernel_launch(void* const* d_in, const int* in_sizes, int n_in,
                              void* d_out, int out_size, void* d_ws, size_t ws_size,
                              hipStream_t stream) {
    const float* uw   = (const float*)d_in[0];
    const float* iw   = (const float*)d_in[1];
    const float* tw   = (const float*)d_in[2];
    const float* vals = (const float*)d_in[3];
    const int*   row  = (const int*)d_in[4];
    const int*   col  = (const int*)d_in[5];
    const int*   users= (const int*)d_in[6];
    const int*   items= (const int*)d_in[7];
    float* out = (float*)d_out;

    // ---- workspace layout (no aliasing; ~96 MB total) ----
    char* ws = (char*)d_ws;
    const size_t NODE_F = (size_t)N_NODES * DIM;       // 9,664,000 elements
    __half* A     = (__half*)ws; ws += NODE_F * 2;     // 19.33 MB
    __half* B     = (__half*)ws; ws += NODE_F * 2;     // 19.33 MB
    float* ACCB   = (float*)ws;  ws += (size_t)2 * BATCH * DIM * 4;
    int*   bcnt   = (int*)ws;    ws += (size_t)NB * 4;
    int*   bptr   = (int*)ws;    ws += (size_t)(NB + 1) * 4;
    int*   rowptr = (int*)ws;    ws += (size_t)(N_NODES + 1) * 4;
    int*   hcnt   = (int*)ws;    ws += (size_t)NPART * NB * 4;   // 1.21 MB
    int*   sync   = (int*)ws;    ws += 64;                       // scanAB counter
    unsigned int* cv = (unsigned int*)ws; ws += (size_t)NNZ * 4; // 16 MB packed
    int2*  cvtmp  = (int2*)ws;   ws += (size_t)NNZ * 8;          // 32 MB

    const int batch_v4 = 2 * BATCH * (DIM / 4);

    // ---- phase0: count + concat + batch_init fused (also zeroes sync) ----
    phase0<<<NPART + CONCAT_BLOCKS + BINIT_BLOCKS, 1024, 0, stream>>>(
        (const float4*)uw, (const float4*)iw, (const float4*)tw, row,
        users, items, (__half2*)A, (float4*)ACCB, hcnt, sync);

    // ---- fused scan + LDS-sorted scatter + bucket sort -> CSR ----
    part_scanAB<<<NB / 4, 256, 0, stream>>>(hcnt, bcnt, bptr, rowptr, sync);
    part_scatter<<<NPART, 1024, 0, stream>>>(row, col, vals, hcnt, bptr, cvtmp);
    bucket_sort<<<NB, 256, 0, stream>>>(bptr, (const long long*)cvtmp, cv, rowptr);

    // ---- layers 1,2: full SpMM (fp16 tables); layer 3: batch rows only ----
    const int spmm_blocks = NB * 16;   // 1180 buckets x 16 sub-tiles (8 rows each)
    spmm_csr<<<spmm_blocks, 256, 0, stream>>>(rowptr, cv, (const __half2*)A,
                                              (__half2*)B);
    batch_add<<<(batch_v4 + 255) / 256, 256, 0, stream>>>(
        B, users, items, (float4*)ACCB);
    spmm_csr<<<spmm_blocks, 256, 0, stream>>>(rowptr, cv, (const __half2*)B,
                                              (__half2*)A);
    batch_add<<<(batch_v4 + 255) / 256, 256, 0, stream>>>(
        A, users, items, (float4*)ACCB);
    spmm_batch<<<(2 * BATCH + 7) / 8, 256, 0, stream>>>(
        rowptr, cv, (const __half2*)A, users, items, ACCB);

    final_dot<<<(BATCH + 3) / 4, 256, 0, stream>>>(ACCB, out);
}

// Round 9
// 404.092 us; speedup vs baseline: 1.1044x; 1.0118x over previous
//
#include <hip/hip_runtime.h>
#include <hip/hip_fp16.h>

#define N_USERS 100000
#define N_ITEMS 50000
#define N_TOPICS 1000
#define N_NODES (N_USERS + N_ITEMS + N_TOPICS)   // 151000
#define DIM 64
#define NNZ 4000000
#define BATCH 16384

#define BROWS 128                                 // rows per bucket
#define NB ((N_NODES + BROWS - 1) / BROWS)        // 1180 buckets
#define NPART 256                                 // partition blocks
#define CHUNK ((NNZ + NPART - 1) / NPART)         // 15625 edges per block
#define SUB 7813                                  // LDS sort sub-chunk
#define SEGCAP 4608                               // LDS seg capacity (36 KB)

// cv entry: (qval14 << 18) | col18 ; val = qval * (1/16384)
#define QSCALE 16384.0f
#define QINV   6.103515625e-05f                   // 1/16384

#define CONCAT_TOTAL (N_NODES * (DIM / 4))        // 2,416,000
#define CONCAT_BLOCKS ((CONCAT_TOTAL + 1023) / 1024)   // 2360
#define BINIT_TOTAL (2 * BATCH * (DIM / 4))       // 524,288
#define BINIT_BLOCKS ((BINIT_TOTAL + 1023) / 1024)     // 512

// ---------------------------------------------------------------------------
// phase0: fused (part_count | concat_init | batch_init) by blockIdx role.
// ---------------------------------------------------------------------------
__global__ void __launch_bounds__(1024)
phase0(const float4* __restrict__ uw,
       const float4* __restrict__ iw,
       const float4* __restrict__ tw,
       const int* __restrict__ row,
       const int* __restrict__ users,
       const int* __restrict__ items,
       __half2* __restrict__ x0,
       float4* __restrict__ accb,
       int* __restrict__ hcnt,
       int* __restrict__ sync) {
    __shared__ int h[NB];
    const int blk = blockIdx.x;
    const int t = threadIdx.x;
    if (blk < NPART) {
        // ---- part_count role ----
        if (blk == 0 && t == 0) *sync = 0;
        for (int i = t; i < NB; i += 1024) h[i] = 0;
        __syncthreads();
        int e0 = blk * CHUNK;
        int e1 = e0 + CHUNK; if (e1 > NNZ) e1 = NNZ;
        for (int e = e0 + t; e < e1; e += 1024) {
            int r = __builtin_nontemporal_load(&row[e]);
            atomicAdd(&h[r >> 7], 1);
        }
        __syncthreads();
        int* dst = hcnt + (size_t)blk * NB;
        for (int i = t; i < NB; i += 1024) dst[i] = h[i];
    } else if (blk < NPART + CONCAT_BLOCKS) {
        // ---- concat_init role ----
        int tid = (blk - NPART) * 1024 + t;
        if (tid >= CONCAT_TOTAL) return;
        int node = tid >> 4;
        int q = tid & 15;
        float4 v;
        if (node < N_USERS)                v = uw[node * 16 + q];
        else if (node < N_USERS + N_ITEMS) v = iw[(node - N_USERS) * 16 + q];
        else                               v = tw[(node - N_USERS - N_ITEMS) * 16 + q];
        x0[tid * 2]     = __floats2half2_rn(v.x, v.y);
        x0[tid * 2 + 1] = __floats2half2_rn(v.z, v.w);
    } else {
        // ---- batch_init role ----
        int tid = (blk - NPART - CONCAT_BLOCKS) * 1024 + t;
        if (tid >= BINIT_TOTAL) return;
        int r = tid >> 4;
        int q = tid & 15;
        float4 v;
        if (r < BATCH) v = uw[(size_t)users[r] * 16 + q];
        else           v = iw[(size_t)items[r - BATCH] * 16 + q];
        accb[tid] = v;
    }
}

// ---------------------------------------------------------------------------
// Fused scanA + scanB (last-block pattern). 295 blocks x 256 threads.
// ---------------------------------------------------------------------------
__global__ void __launch_bounds__(256)
part_scanAB(int* __restrict__ hcnt,
            int* __restrict__ bcnt,
            int* __restrict__ bptr,
            int* __restrict__ rowptr,
            int* __restrict__ sync) {
    const int t = threadIdx.x;
    const int lane = t & 63;
    const int wid = t >> 6;
    int b = blockIdx.x * 4 + wid;     // grid sized so b < NB always
    int carry = 0;
    for (int base = 0; base < NPART; base += 64) {
        int g = base + lane;
        int v = hcnt[(size_t)g * NB + b];
        int x = v;
        #pragma unroll
        for (int off = 1; off < 64; off <<= 1) {
            int y = __shfl_up(x, off, 64);
            if (lane >= off) x += y;
        }
        int tot = __shfl(x, 63, 64);
        hcnt[(size_t)g * NB + b] = carry + x - v;
        carry += tot;
    }
    if (lane == 0) bcnt[b] = carry;
    __syncthreads();
    __threadfence();
    __shared__ int lastFlag;
    if (t == 0) lastFlag = (atomicAdd(sync, 1) == (int)gridDim.x - 1);
    __syncthreads();
    if (!lastFlag) return;

    // ---- scanB over bcnt[0..NB) with 256 threads ----
    __shared__ int wsum[4];
    __shared__ int carry_s;
    if (t == 0) carry_s = 0;
    __syncthreads();
    for (int base = 0; base < NB; base += 256) {
        int i = base + t;
        int v = (i < NB) ? bcnt[i] : 0;
        int x = v;
        #pragma unroll
        for (int off = 1; off < 64; off <<= 1) {
            int y = __shfl_up(x, off, 64);
            if (lane >= off) x += y;
        }
        if (lane == 63) wsum[wid] = x;
        __syncthreads();
        int wbase = 0;
        for (int w = 0; w < wid; ++w) wbase += wsum[w];
        int excl = carry_s + wbase + (x - v);
        if (i < NB) bptr[i] = excl;
        __syncthreads();
        if (t == 255) carry_s = excl + v;
        __syncthreads();
    }
    if (t == 0) { bptr[NB] = NNZ; rowptr[N_NODES] = NNZ; }
}

// ---------------------------------------------------------------------------
// Partition phase 3: block-local counting sort -> DENSE writes.
// ---------------------------------------------------------------------------
__global__ void __launch_bounds__(1024)
part_scatter(const int* __restrict__ row,
             const int* __restrict__ col,
             const float* __restrict__ vals,
             const int* __restrict__ hcnt,
             const int* __restrict__ bptr,
             int2* __restrict__ cvtmp) {
    __shared__ int2 sorted[SUB];           // 62.5 KB
    __shared__ unsigned short bktSorted[SUB];  // 15.6 KB
    __shared__ int cnt_s[NB];
    __shared__ int cur_s[NB];
    __shared__ int gcur[NB];               // running global dst per bucket
    __shared__ int wsum[16];
    __shared__ int carry_s;
    const int g = blockIdx.x;
    const int t = threadIdx.x;
    const int lane = t & 63;
    const int wid = t >> 6;
    const int* hoff = hcnt + (size_t)g * NB;
    for (int i = t; i < NB; i += 1024) gcur[i] = bptr[i] + hoff[i];
    int e0 = g * CHUNK;
    int e1 = e0 + CHUNK; if (e1 > NNZ) e1 = NNZ;

    for (int s0 = e0; s0 < e1; s0 += SUB) {
        int n = e1 - s0; if (n > SUB) n = SUB;
        for (int i = t; i < NB; i += 1024) cnt_s[i] = 0;
        if (t == 0) carry_s = 0;
        __syncthreads();
        // pass A: histogram by bucket
        for (int j = t; j < n; j += 1024) {
            int r = __builtin_nontemporal_load(&row[s0 + j]);
            atomicAdd(&cnt_s[r >> 7], 1);
        }
        __syncthreads();
        // exclusive block-scan cnt_s -> cur_s (local bucket starts)
        for (int base = 0; base < NB; base += 1024) {
            int i = base + t;
            int v = (i < NB) ? cnt_s[i] : 0;
            int x = v;
            #pragma unroll
            for (int off = 1; off < 64; off <<= 1) {
                int y = __shfl_up(x, off, 64);
                if (lane >= off) x += y;
            }
            if (lane == 63) wsum[wid] = x;
            __syncthreads();
            int wbase = 0;
            for (int w = 0; w < wid; ++w) wbase += wsum[w];
            int excl = carry_s + wbase + (x - v);
            if (i < NB) cur_s[i] = excl;
            __syncthreads();
            if (t == 1023) carry_s = excl + v;
            __syncthreads();
        }
        // pass B: scatter into LDS in bucket-sorted order; record bucket
        for (int j = t; j < n; j += 1024) {
            int r = __builtin_nontemporal_load(&row[s0 + j]);
            int c = __builtin_nontemporal_load(&col[s0 + j]);
            float v = __builtin_nontemporal_load(&vals[s0 + j]);
            int b = r >> 7;
            int p = atomicAdd(&cur_s[b], 1);
            sorted[p] = make_int2(((r & (BROWS - 1)) << 18) | c, __float_as_int(v));
            bktSorted[p] = (unsigned short)b;
        }
        __syncthreads();
        // pass C: dense global write (local start = cur_s[b] - cnt_s[b]).
        for (int j = t; j < n; j += 1024) {
            int b = bktSorted[j];
            int lb = cur_s[b] - cnt_s[b];
            cvtmp[gcur[b] + (j - lb)] = sorted[j];
        }
        __syncthreads();
        for (int i = t; i < NB; i += 1024) gcur[i] += cnt_s[i];
        __syncthreads();
    }
}

// ---------------------------------------------------------------------------
// Bucket-local counting sort -> row-sorted CSR (cv, packed 4B) + rowptr.
// ---------------------------------------------------------------------------
__global__ void __launch_bounds__(256)
bucket_sort(const int* __restrict__ bptr,
            const long long* __restrict__ cvtmp,
            unsigned int* __restrict__ cv,
            int* __restrict__ rowptr) {
    __shared__ int2 seg[SEGCAP];     // 36 KB
    __shared__ int cnt[BROWS];
    __shared__ int cur[BROWS];
    const int t = threadIdx.x;
    const int b = blockIdx.x;
    const int beg = bptr[b];
    const int end = bptr[b + 1];
    const int n = end - beg;

    for (int i = t; i < BROWS; i += 256) cnt[i] = 0;
    const bool lds_path = (n <= SEGCAP);

    if (lds_path) {
        for (int j = t; j < n; j += 256) {
            long long e = __builtin_nontemporal_load(&cvtmp[beg + j]);
            seg[j] = make_int2((int)e, (int)(e >> 32));
        }
    }
    __syncthreads();

    if (lds_path) {
        for (int j = t; j < n; j += 256)
            atomicAdd(&cnt[(seg[j].x >> 18) & (BROWS - 1)], 1);
    } else {
        for (int j = beg + t; j < end; j += 256) {
            long long e = cvtmp[j];
            atomicAdd(&cnt[((int)e >> 18) & (BROWS - 1)], 1);
        }
    }
    __syncthreads();

    if (t < 64) {
        int lane = t;
        int v0 = cnt[lane];
        int v1 = cnt[64 + lane];
        int x0 = v0;
        #pragma unroll
        for (int off = 1; off < 64; off <<= 1) {
            int y = __shfl_up(x0, off, 64);
            if (lane >= off) x0 += y;
        }
        int tot0 = __shfl(x0, 63, 64);
        int x1 = v1;
        #pragma unroll
        for (int off = 1; off < 64; off <<= 1) {
            int y = __shfl_up(x1, off, 64);
            if (lane >= off) x1 += y;
        }
        x1 += tot0;
        int e0 = x0 - v0;
        int e1 = x1 - v1;
        cur[lane] = e0;
        cur[64 + lane] = e1;
        int rowbase = b * BROWS;
        if (rowbase + lane < N_NODES)      rowptr[rowbase + lane] = beg + e0;
        if (rowbase + 64 + lane < N_NODES) rowptr[rowbase + 64 + lane] = beg + e1;
    }
    __syncthreads();

    if (lds_path) {
        for (int j = t; j < n; j += 256) {
            int2 e = seg[j];
            int p = atomicAdd(&cur[(e.x >> 18) & (BROWS - 1)], 1);
            float v = __int_as_float(e.y);
            unsigned int qv = (unsigned int)(v * QSCALE + 0.5f);
            if (qv > 16383u) qv = 16383u;
            cv[beg + p] = (qv << 18) | (unsigned int)(e.x & 0x3FFFF);
        }
    } else {
        for (int j = beg + t; j < end; j += 256) {
            long long e = cvtmp[j];
            int lo = (int)e;
            float v = __int_as_float((int)(e >> 32));
            int p = atomicAdd(&cur[(lo >> 18) & (BROWS - 1)], 1);
            unsigned int qv = (unsigned int)(v * QSCALE + 0.5f);
            if (qv > 16383u) qv = 16383u;
            cv[beg + p] = (qv << 18) | (unsigned int)(lo & 0x3FFFF);
        }
    }
}

// ---------------------------------------------------------------------------
// SpMM over CSR, FP16 tables. R9: QUARTER-WAVE PER ROW — wave = 4 adjacent
// rows, 16 lanes each; per-lane gather is uint2 (8 B, 4 dims), so one
// instruction stream serves 4 edges (was 2): ~35% fewer VALU/VMEM insts
// per edge at identical requested bytes. Unroll 8/4/1 tiers; nt 8-B y-store.
// ---------------------------------------------------------------------------
__global__ void spmm_csr(const int* __restrict__ rowptr,
                         const unsigned int* __restrict__ cv,
                         const __half2* __restrict__ x2,
                         __half2* __restrict__ y2) {
    int bucket = blockIdx.x >> 3;
    int sub = blockIdx.x & 7;
    int lane = threadIdx.x & 63;
    int grp = lane >> 4;
    int d = lane & 15;
    int r = bucket * BROWS + sub * 16 + (threadIdx.x >> 6) * 4 + grp;
    if (r >= N_NODES) return;
    const uint2* xv = (const uint2*)x2;   // 16 uint2 per row
    int beg = rowptr[r];
    int end = rowptr[r + 1];
    float ax0 = 0.0f, ay0 = 0.0f, ax1 = 0.0f, ay1 = 0.0f;
    int j = beg;
    for (; j + 7 < end; j += 8) {         // 8 x 8B gathers in flight
        unsigned int u[8];
        uint2 h[8];
        #pragma unroll
        for (int k = 0; k < 8; ++k) u[k] = cv[j + k];
        #pragma unroll
        for (int k = 0; k < 8; ++k) h[k] = xv[(size_t)(u[k] & 0x3FFFF) * 16 + d];
        #pragma unroll
        for (int k = 0; k < 8; ++k) {
            float v = (float)(u[k] >> 18) * QINV;
            __half2 h0, h1;
            __builtin_memcpy(&h0, &h[k].x, 4);
            __builtin_memcpy(&h1, &h[k].y, 4);
            float2 f0 = __half22float2(h0);
            float2 f1 = __half22float2(h1);
            ax0 = fmaf(v, f0.x, ax0); ay0 = fmaf(v, f0.y, ay0);
            ax1 = fmaf(v, f1.x, ax1); ay1 = fmaf(v, f1.y, ay1);
        }
    }
    for (; j + 3 < end; j += 4) {
        unsigned int u[4];
        uint2 h[4];
        #pragma unroll
        for (int k = 0; k < 4; ++k) u[k] = cv[j + k];
        #pragma unroll
        for (int k = 0; k < 4; ++k) h[k] = xv[(size_t)(u[k] & 0x3FFFF) * 16 + d];
        #pragma unroll
        for (int k = 0; k < 4; ++k) {
            float v = (float)(u[k] >> 18) * QINV;
            __half2 h0, h1;
            __builtin_memcpy(&h0, &h[k].x, 4);
            __builtin_memcpy(&h1, &h[k].y, 4);
            float2 f0 = __half22float2(h0);
            float2 f1 = __half22float2(h1);
            ax0 = fmaf(v, f0.x, ax0); ay0 = fmaf(v, f0.y, ay0);
            ax1 = fmaf(v, f1.x, ax1); ay1 = fmaf(v, f1.y, ay1);
        }
    }
    for (; j < end; ++j) {
        unsigned int u = cv[j];
        uint2 h = xv[(size_t)(u & 0x3FFFF) * 16 + d];
        float v = (float)(u >> 18) * QINV;
        __half2 h0, h1;
        __builtin_memcpy(&h0, &h.x, 4);
        __builtin_memcpy(&h1, &h.y, 4);
        float2 f0 = __half22float2(h0);
        float2 f1 = __half22float2(h1);
        ax0 = fmaf(v, f0.x, ax0); ay0 = fmaf(v, f0.y, ay0);
        ax1 = fmaf(v, f1.x, ax1); ay1 = fmaf(v, f1.y, ay1);
    }
    __half2 o0 = __floats2half2_rn(ax0, ay0);
    __half2 o1 = __floats2half2_rn(ax1, ay1);
    unsigned int w0, w1;
    __builtin_memcpy(&w0, &o0, 4);
    __builtin_memcpy(&w1, &o1, 4);
    unsigned long long ob = (unsigned long long)w0 |
                            ((unsigned long long)w1 << 32);
    __builtin_nontemporal_store(ob,
        (unsigned long long*)&y2[(size_t)r * 32 + 2 * d]);
}

// ---------------------------------------------------------------------------
// Layer-3 SpMM restricted to batch rows, same quarter-wave structure;
// fp32 accumulation straight into ACCB (float4 RMW: dims 4d..4d+3).
// ---------------------------------------------------------------------------
__global__ void spmm_batch(const int* __restrict__ rowptr,
                           const unsigned int* __restrict__ cv,
                           const __half2* __restrict__ x2,
                           const int* __restrict__ users,
                           const int* __restrict__ items,
                           float* __restrict__ accb) {
    int lane = threadIdx.x & 63;
    int grp = lane >> 4;
    int d = lane & 15;
    int b = blockIdx.x * 16 + (threadIdx.x >> 6) * 4 + grp;
    if (b >= 2 * BATCH) return;
    const uint2* xv = (const uint2*)x2;
    int r = (b < BATCH) ? users[b] : (N_USERS + items[b - BATCH]);
    int beg = rowptr[r];
    int end = rowptr[r + 1];
    float ax0 = 0.0f, ay0 = 0.0f, ax1 = 0.0f, ay1 = 0.0f;
    int j = beg;
    for (; j + 7 < end; j += 8) {
        unsigned int u[8];
        uint2 h[8];
        #pragma unroll
        for (int k = 0; k < 8; ++k) u[k] = cv[j + k];
        #pragma unroll
        for (int k = 0; k < 8; ++k) h[k] = xv[(size_t)(u[k] & 0x3FFFF) * 16 + d];
        #pragma unroll
        for (int k = 0; k < 8; ++k) {
            float v = (float)(u[k] >> 18) * QINV;
            __half2 h0, h1;
            __builtin_memcpy(&h0, &h[k].x, 4);
            __builtin_memcpy(&h1, &h[k].y, 4);
            float2 f0 = __half22float2(h0);
            float2 f1 = __half22float2(h1);
            ax0 = fmaf(v, f0.x, ax0); ay0 = fmaf(v, f0.y, ay0);
            ax1 = fmaf(v, f1.x, ax1); ay1 = fmaf(v, f1.y, ay1);
        }
    }
    for (; j + 3 < end; j += 4) {
        unsigned int u[4];
        uint2 h[4];
        #pragma unroll
        for (int k = 0; k < 4; ++k) u[k] = cv[j + k];
        #pragma unroll
        for (int k = 0; k < 4; ++k) h[k] = xv[(size_t)(u[k] & 0x3FFFF) * 16 + d];
        #pragma unroll
        for (int k = 0; k < 4; ++k) {
            float v = (float)(u[k] >> 18) * QINV;
            __half2 h0, h1;
            __builtin_memcpy(&h0, &h[k].x, 4);
            __builtin_memcpy(&h1, &h[k].y, 4);
            float2 f0 = __half22float2(h0);
            float2 f1 = __half22float2(h1);
            ax0 = fmaf(v, f0.x, ax0); ay0 = fmaf(v, f0.y, ay0);
            ax1 = fmaf(v, f1.x, ax1); ay1 = fmaf(v, f1.y, ay1);
        }
    }
    for (; j < end; ++j) {
        unsigned int u = cv[j];
        uint2 h = xv[(size_t)(u & 0x3FFFF) * 16 + d];
        float v = (float)(u >> 18) * QINV;
        __half2 h0, h1;
        __builtin_memcpy(&h0, &h.x, 4);
        __builtin_memcpy(&h1, &h.y, 4);
        float2 f0 = __half22float2(h0);
        float2 f1 = __half22float2(h1);
        ax0 = fmaf(v, f0.x, ax0); ay0 = fmaf(v, f0.y, ay0);
        ax1 = fmaf(v, f1.x, ax1); ay1 = fmaf(v, f1.y, ay1);
    }
    float4* a4 = (float4*)(accb + (size_t)b * 64 + 4 * d);
    float4 o = *a4;
    o.x += ax0; o.y += ay0; o.z += ax1; o.w += ay1;
    *a4 = o;
}

// ---------------------------------------------------------------------------
// Batch accumulator add from fp16 node table (layers 1,2).
// ---------------------------------------------------------------------------
__global__ void batch_add(const __half* __restrict__ emb,
                          const int* __restrict__ users,
                          const int* __restrict__ items,
                          float4* __restrict__ accb) {
    int tid = blockIdx.x * blockDim.x + threadIdx.x;
    const int total = 2 * BATCH * (DIM / 4);
    if (tid >= total) return;
    int r = tid >> 4;
    int q = tid & 15;
    int node = (r < BATCH) ? users[r] : (N_USERS + items[r - BATCH]);
    const __half2* e2 = (const __half2*)(emb + (size_t)node * 64 + q * 4);
    float2 lo = __half22float2(e2[0]);
    float2 hi = __half22float2(e2[1]);
    float4 a = accb[tid];
    a.x += lo.x; a.y += lo.y; a.z += hi.x; a.w += hi.y;
    accb[tid] = a;
}

// ---------------------------------------------------------------------------
// Final dot: out[b] = (accb[b] . accb[BATCH+b]) / 16
// ---------------------------------------------------------------------------
__global__ void final_dot(const float* __restrict__ accb,
                          float* __restrict__ out) {
    int b = blockIdx.x * 4 + (threadIdx.x >> 6);
    int lane = threadIdx.x & 63;
    if (b >= BATCH) return;
    float pu = accb[(size_t)b * 64 + lane];
    float pi = accb[(size_t)(BATCH + b) * 64 + lane];
    float p = pu * pi;
    #pragma unroll
    for (int off = 32; off > 0; off >>= 1)
        p += __shfl_down(p, off, 64);
    if (lane == 0) out[b] = p * (1.0f / 16.0f);
}

extern "C" void kernel_launch(void* const* d_in, const int* in_sizes, int n_in,
                              void* d_out, int out_size, void* d_ws, size_t ws_size,
                              hipStream_t stream) {
    const float* uw   = (const float*)d_in[0];
    const float* iw   = (const float*)d_in[1];
    const float* tw   = (const float*)d_in[2];
    const float* vals = (const float*)d_in[3];
    const int*   row  = (const int*)d_in[4];
    const int*   col  = (const int*)d_in[5];
    const int*   users= (const int*)d_in[6];
    const int*   items= (const int*)d_in[7];
    float* out = (float*)d_out;

    // ---- workspace layout (no aliasing; ~96 MB total) ----
    char* ws = (char*)d_ws;
    const size_t NODE_F = (size_t)N_NODES * DIM;       // 9,664,000 elements
    __half* A     = (__half*)ws; ws += NODE_F * 2;     // 19.33 MB
    __half* B     = (__half*)ws; ws += NODE_F * 2;     // 19.33 MB
    float* ACCB   = (float*)ws;  ws += (size_t)2 * BATCH * DIM * 4;
    int*   bcnt   = (int*)ws;    ws += (size_t)NB * 4;
    int*   bptr   = (int*)ws;    ws += (size_t)(NB + 1) * 4;
    int*   rowptr = (int*)ws;    ws += (size_t)(N_NODES + 1) * 4;
    int*   hcnt   = (int*)ws;    ws += (size_t)NPART * NB * 4;   // 1.21 MB
    int*   sync   = (int*)ws;    ws += 64;                       // scanAB counter
    unsigned int* cv = (unsigned int*)ws; ws += (size_t)NNZ * 4; // 16 MB packed
    int2*  cvtmp  = (int2*)ws;   ws += (size_t)NNZ * 8;          // 32 MB

    const int batch_v4 = 2 * BATCH * (DIM / 4);

    // ---- phase0: count + concat + batch_init fused (also zeroes sync) ----
    phase0<<<NPART + CONCAT_BLOCKS + BINIT_BLOCKS, 1024, 0, stream>>>(
        (const float4*)uw, (const float4*)iw, (const float4*)tw, row,
        users, items, (__half2*)A, (float4*)ACCB, hcnt, sync);

    // ---- fused scan + LDS-sorted scatter + bucket sort -> CSR ----
    part_scanAB<<<NB / 4, 256, 0, stream>>>(hcnt, bcnt, bptr, rowptr, sync);
    part_scatter<<<NPART, 1024, 0, stream>>>(row, col, vals, hcnt, bptr, cvtmp);
    bucket_sort<<<NB, 256, 0, stream>>>(bptr, (const long long*)cvtmp, cv, rowptr);

    // ---- layers 1,2: full SpMM (fp16 tables); layer 3: batch rows only ----
    const int spmm_blocks = NB * 8;   // 1180 buckets x 8 sub-tiles (16 rows each)
    spmm_csr<<<spmm_blocks, 256, 0, stream>>>(rowptr, cv, (const __half2*)A,
                                              (__half2*)B);
    batch_add<<<(batch_v4 + 255) / 256, 256, 0, stream>>>(
        B, users, items, (float4*)ACCB);
    spmm_csr<<<spmm_blocks, 256, 0, stream>>>(rowptr, cv, (const __half2*)B,
                                              (__half2*)A);
    batch_add<<<(batch_v4 + 255) / 256, 256, 0, stream>>>(
        A, users, items, (float4*)ACCB);
    spmm_batch<<<(2 * BATCH + 15) / 16, 256, 0, stream>>>(
        rowptr, cv, (const __half2*)A, users, items, ACCB);

    final_dot<<<(BATCH + 3) / 4, 256, 0, stream>>>(ACCB, out);
}

// Round 10
// 394.342 us; speedup vs baseline: 1.1317x; 1.0247x over previous
//
#include <hip/hip_runtime.h>
#include <hip/hip_fp16.h>

#define N_USERS 100000
#define N_ITEMS 50000
#define N_TOPICS 1000
#define N_NODES (N_USERS + N_ITEMS + N_TOPICS)   // 151000
#define DIM 64
#define NNZ 4000000
#define BATCH 16384

#define BROWS 128                                 // rows per bucket
#define NB ((N_NODES + BROWS - 1) / BROWS)        // 1180 buckets
#define NPART 256                                 // partition blocks
#define CHUNK ((NNZ + NPART - 1) / NPART)         // 15625 edges per block
#define SUB 7813                                  // LDS sort sub-chunk
#define SEGCAP 4608                               // LDS seg capacity (36 KB)

// cv entry: (qval14 << 18) | col18 ; val = qval * (1/16384)
#define QSCALE 16384.0f
#define QINV   6.103515625e-05f                   // 1/16384

#define CONCAT_TOTAL (N_NODES * (DIM / 4))        // 2,416,000
#define CONCAT_BLOCKS ((CONCAT_TOTAL + 1023) / 1024)   // 2360
#define BINIT_TOTAL (2 * BATCH * (DIM / 4))       // 524,288
#define BINIT_BLOCKS ((BINIT_TOTAL + 1023) / 1024)     // 512

// ---------------------------------------------------------------------------
// phase0: fused (part_count | concat_init | batch_init) by blockIdx role.
// ---------------------------------------------------------------------------
__global__ void __launch_bounds__(1024)
phase0(const float4* __restrict__ uw,
       const float4* __restrict__ iw,
       const float4* __restrict__ tw,
       const int* __restrict__ row,
       const int* __restrict__ users,
       const int* __restrict__ items,
       __half2* __restrict__ x0,
       float4* __restrict__ accb,
       int* __restrict__ hcnt,
       int* __restrict__ sync) {
    __shared__ int h[NB];
    const int blk = blockIdx.x;
    const int t = threadIdx.x;
    if (blk < NPART) {
        // ---- part_count role ----
        if (blk == 0 && t == 0) *sync = 0;
        for (int i = t; i < NB; i += 1024) h[i] = 0;
        __syncthreads();
        int e0 = blk * CHUNK;
        int e1 = e0 + CHUNK; if (e1 > NNZ) e1 = NNZ;
        for (int e = e0 + t; e < e1; e += 1024) {
            int r = __builtin_nontemporal_load(&row[e]);
            atomicAdd(&h[r >> 7], 1);
        }
        __syncthreads();
        int* dst = hcnt + (size_t)blk * NB;
        for (int i = t; i < NB; i += 1024) dst[i] = h[i];
    } else if (blk < NPART + CONCAT_BLOCKS) {
        // ---- concat_init role ----
        int tid = (blk - NPART) * 1024 + t;
        if (tid >= CONCAT_TOTAL) return;
        int node = tid >> 4;
        int q = tid & 15;
        float4 v;
        if (node < N_USERS)                v = uw[node * 16 + q];
        else if (node < N_USERS + N_ITEMS) v = iw[(node - N_USERS) * 16 + q];
        else                               v = tw[(node - N_USERS - N_ITEMS) * 16 + q];
        x0[tid * 2]     = __floats2half2_rn(v.x, v.y);
        x0[tid * 2 + 1] = __floats2half2_rn(v.z, v.w);
    } else {
        // ---- batch_init role ----
        int tid = (blk - NPART - CONCAT_BLOCKS) * 1024 + t;
        if (tid >= BINIT_TOTAL) return;
        int r = tid >> 4;
        int q = tid & 15;
        float4 v;
        if (r < BATCH) v = uw[(size_t)users[r] * 16 + q];
        else           v = iw[(size_t)items[r - BATCH] * 16 + q];
        accb[tid] = v;
    }
}

// ---------------------------------------------------------------------------
// Fused scanA + scanB (last-block pattern). 295 blocks x 256 threads.
// ---------------------------------------------------------------------------
__global__ void __launch_bounds__(256)
part_scanAB(int* __restrict__ hcnt,
            int* __restrict__ bcnt,
            int* __restrict__ bptr,
            int* __restrict__ rowptr,
            int* __restrict__ sync) {
    const int t = threadIdx.x;
    const int lane = t & 63;
    const int wid = t >> 6;
    int b = blockIdx.x * 4 + wid;     // grid sized so b < NB always
    int carry = 0;
    for (int base = 0; base < NPART; base += 64) {
        int g = base + lane;
        int v = hcnt[(size_t)g * NB + b];
        int x = v;
        #pragma unroll
        for (int off = 1; off < 64; off <<= 1) {
            int y = __shfl_up(x, off, 64);
            if (lane >= off) x += y;
        }
        int tot = __shfl(x, 63, 64);
        hcnt[(size_t)g * NB + b] = carry + x - v;
        carry += tot;
    }
    if (lane == 0) bcnt[b] = carry;
    __syncthreads();
    __threadfence();
    __shared__ int lastFlag;
    if (t == 0) lastFlag = (atomicAdd(sync, 1) == (int)gridDim.x - 1);
    __syncthreads();
    if (!lastFlag) return;

    // ---- scanB over bcnt[0..NB) with 256 threads ----
    __shared__ int wsum[4];
    __shared__ int carry_s;
    if (t == 0) carry_s = 0;
    __syncthreads();
    for (int base = 0; base < NB; base += 256) {
        int i = base + t;
        int v = (i < NB) ? bcnt[i] : 0;
        int x = v;
        #pragma unroll
        for (int off = 1; off < 64; off <<= 1) {
            int y = __shfl_up(x, off, 64);
            if (lane >= off) x += y;
        }
        if (lane == 63) wsum[wid] = x;
        __syncthreads();
        int wbase = 0;
        for (int w = 0; w < wid; ++w) wbase += wsum[w];
        int excl = carry_s + wbase + (x - v);
        if (i < NB) bptr[i] = excl;
        __syncthreads();
        if (t == 255) carry_s = excl + v;
        __syncthreads();
    }
    if (t == 0) { bptr[NB] = NNZ; rowptr[N_NODES] = NNZ; }
}

// ---------------------------------------------------------------------------
// Partition phase 3: block-local counting sort -> DENSE writes.
// ---------------------------------------------------------------------------
__global__ void __launch_bounds__(1024)
part_scatter(const int* __restrict__ row,
             const int* __restrict__ col,
             const float* __restrict__ vals,
             const int* __restrict__ hcnt,
             const int* __restrict__ bptr,
             int2* __restrict__ cvtmp) {
    __shared__ int2 sorted[SUB];           // 62.5 KB
    __shared__ unsigned short bktSorted[SUB];  // 15.6 KB
    __shared__ int cnt_s[NB];
    __shared__ int cur_s[NB];
    __shared__ int gcur[NB];               // running global dst per bucket
    __shared__ int wsum[16];
    __shared__ int carry_s;
    const int g = blockIdx.x;
    const int t = threadIdx.x;
    const int lane = t & 63;
    const int wid = t >> 6;
    const int* hoff = hcnt + (size_t)g * NB;
    for (int i = t; i < NB; i += 1024) gcur[i] = bptr[i] + hoff[i];
    int e0 = g * CHUNK;
    int e1 = e0 + CHUNK; if (e1 > NNZ) e1 = NNZ;

    for (int s0 = e0; s0 < e1; s0 += SUB) {
        int n = e1 - s0; if (n > SUB) n = SUB;
        for (int i = t; i < NB; i += 1024) cnt_s[i] = 0;
        if (t == 0) carry_s = 0;
        __syncthreads();
        // pass A: histogram by bucket
        for (int j = t; j < n; j += 1024) {
            int r = __builtin_nontemporal_load(&row[s0 + j]);
            atomicAdd(&cnt_s[r >> 7], 1);
        }
        __syncthreads();
        // exclusive block-scan cnt_s -> cur_s (local bucket starts)
        for (int base = 0; base < NB; base += 1024) {
            int i = base + t;
            int v = (i < NB) ? cnt_s[i] : 0;
            int x = v;
            #pragma unroll
            for (int off = 1; off < 64; off <<= 1) {
                int y = __shfl_up(x, off, 64);
                if (lane >= off) x += y;
            }
            if (lane == 63) wsum[wid] = x;
            __syncthreads();
            int wbase = 0;
            for (int w = 0; w < wid; ++w) wbase += wsum[w];
            int excl = carry_s + wbase + (x - v);
            if (i < NB) cur_s[i] = excl;
            __syncthreads();
            if (t == 1023) carry_s = excl + v;
            __syncthreads();
        }
        // pass B: scatter into LDS in bucket-sorted order; record bucket
        for (int j = t; j < n; j += 1024) {
            int r = __builtin_nontemporal_load(&row[s0 + j]);
            int c = __builtin_nontemporal_load(&col[s0 + j]);
            float v = __builtin_nontemporal_load(&vals[s0 + j]);
            int b = r >> 7;
            int p = atomicAdd(&cur_s[b], 1);
            sorted[p] = make_int2(((r & (BROWS - 1)) << 18) | c, __float_as_int(v));
            bktSorted[p] = (unsigned short)b;
        }
        __syncthreads();
        // pass C: dense global write (local start = cur_s[b] - cnt_s[b]).
        for (int j = t; j < n; j += 1024) {
            int b = bktSorted[j];
            int lb = cur_s[b] - cnt_s[b];
            cvtmp[gcur[b] + (j - lb)] = sorted[j];
        }
        __syncthreads();
        for (int i = t; i < NB; i += 1024) gcur[i] += cnt_s[i];
        __syncthreads();
    }
}

// ---------------------------------------------------------------------------
// Bucket-local counting sort -> row-sorted CSR (cv, packed 4B) + rowptr.
// R10: 512 threads (was 256) — halves the serial trip count of the seg
// load and both atomic passes; 37 KB LDS still allows 4 blocks/CU.
// ---------------------------------------------------------------------------
__global__ void __launch_bounds__(512)
bucket_sort(const int* __restrict__ bptr,
            const long long* __restrict__ cvtmp,
            unsigned int* __restrict__ cv,
            int* __restrict__ rowptr) {
    __shared__ int2 seg[SEGCAP];     // 36 KB
    __shared__ int cnt[BROWS];
    __shared__ int cur[BROWS];
    const int t = threadIdx.x;
    const int b = blockIdx.x;
    const int beg = bptr[b];
    const int end = bptr[b + 1];
    const int n = end - beg;

    for (int i = t; i < BROWS; i += 512) cnt[i] = 0;
    const bool lds_path = (n <= SEGCAP);

    if (lds_path) {
        for (int j = t; j < n; j += 512) {
            long long e = __builtin_nontemporal_load(&cvtmp[beg + j]);
            seg[j] = make_int2((int)e, (int)(e >> 32));
        }
    }
    __syncthreads();

    if (lds_path) {
        for (int j = t; j < n; j += 512)
            atomicAdd(&cnt[(seg[j].x >> 18) & (BROWS - 1)], 1);
    } else {
        for (int j = beg + t; j < end; j += 512) {
            long long e = cvtmp[j];
            atomicAdd(&cnt[((int)e >> 18) & (BROWS - 1)], 1);
        }
    }
    __syncthreads();

    if (t < 64) {
        int lane = t;
        int v0 = cnt[lane];
        int v1 = cnt[64 + lane];
        int x0 = v0;
        #pragma unroll
        for (int off = 1; off < 64; off <<= 1) {
            int y = __shfl_up(x0, off, 64);
            if (lane >= off) x0 += y;
        }
        int tot0 = __shfl(x0, 63, 64);
        int x1 = v1;
        #pragma unroll
        for (int off = 1; off < 64; off <<= 1) {
            int y = __shfl_up(x1, off, 64);
            if (lane >= off) x1 += y;
        }
        x1 += tot0;
        int e0 = x0 - v0;
        int e1 = x1 - v1;
        cur[lane] = e0;
        cur[64 + lane] = e1;
        int rowbase = b * BROWS;
        if (rowbase + lane < N_NODES)      rowptr[rowbase + lane] = beg + e0;
        if (rowbase + 64 + lane < N_NODES) rowptr[rowbase + 64 + lane] = beg + e1;
    }
    __syncthreads();

    if (lds_path) {
        for (int j = t; j < n; j += 512) {
            int2 e = seg[j];
            int p = atomicAdd(&cur[(e.x >> 18) & (BROWS - 1)], 1);
            float v = __int_as_float(e.y);
            unsigned int qv = (unsigned int)(v * QSCALE + 0.5f);
            if (qv > 16383u) qv = 16383u;
            cv[beg + p] = (qv << 18) | (unsigned int)(e.x & 0x3FFFF);
        }
    } else {
        for (int j = beg + t; j < end; j += 512) {
            long long e = cvtmp[j];
            int lo = (int)e;
            float v = __int_as_float((int)(e >> 32));
            int p = atomicAdd(&cur[(lo >> 18) & (BROWS - 1)], 1);
            unsigned int qv = (unsigned int)(v * QSCALE + 0.5f);
            if (qv > 16383u) qv = 16383u;
            cv[beg + p] = (qv << 18) | (unsigned int)(lo & 0x3FFFF);
        }
    }
}

// ---------------------------------------------------------------------------
// SpMM over CSR, FP16 tables. QUARTER-WAVE PER ROW — wave = 4 adjacent
// rows, 16 lanes each; 8-B uint2 gathers; unroll 8/4/1; nt 8-B y-store.
// ---------------------------------------------------------------------------
__global__ void spmm_csr(const int* __restrict__ rowptr,
                         const unsigned int* __restrict__ cv,
                         const __half2* __restrict__ x2,
                         __half2* __restrict__ y2) {
    int bucket = blockIdx.x >> 3;
    int sub = blockIdx.x & 7;
    int lane = threadIdx.x & 63;
    int grp = lane >> 4;
    int d = lane & 15;
    int r = bucket * BROWS + sub * 16 + (threadIdx.x >> 6) * 4 + grp;
    if (r >= N_NODES) return;
    const uint2* xv = (const uint2*)x2;   // 16 uint2 per row
    int beg = rowptr[r];
    int end = rowptr[r + 1];
    float ax0 = 0.0f, ay0 = 0.0f, ax1 = 0.0f, ay1 = 0.0f;
    int j = beg;
    for (; j + 7 < end; j += 8) {         // 8 x 8B gathers in flight
        unsigned int u[8];
        uint2 h[8];
        #pragma unroll
        for (int k = 0; k < 8; ++k) u[k] = cv[j + k];
        #pragma unroll
        for (int k = 0; k < 8; ++k) h[k] = xv[(size_t)(u[k] & 0x3FFFF) * 16 + d];
        #pragma unroll
        for (int k = 0; k < 8; ++k) {
            float v = (float)(u[k] >> 18) * QINV;
            __half2 h0, h1;
            __builtin_memcpy(&h0, &h[k].x, 4);
            __builtin_memcpy(&h1, &h[k].y, 4);
            float2 f0 = __half22float2(h0);
            float2 f1 = __half22float2(h1);
            ax0 = fmaf(v, f0.x, ax0); ay0 = fmaf(v, f0.y, ay0);
            ax1 = fmaf(v, f1.x, ax1); ay1 = fmaf(v, f1.y, ay1);
        }
    }
    for (; j + 3 < end; j += 4) {
        unsigned int u[4];
        uint2 h[4];
        #pragma unroll
        for (int k = 0; k < 4; ++k) u[k] = cv[j + k];
        #pragma unroll
        for (int k = 0; k < 4; ++k) h[k] = xv[(size_t)(u[k] & 0x3FFFF) * 16 + d];
        #pragma unroll
        for (int k = 0; k < 4; ++k) {
            float v = (float)(u[k] >> 18) * QINV;
            __half2 h0, h1;
            __builtin_memcpy(&h0, &h[k].x, 4);
            __builtin_memcpy(&h1, &h[k].y, 4);
            float2 f0 = __half22float2(h0);
            float2 f1 = __half22float2(h1);
            ax0 = fmaf(v, f0.x, ax0); ay0 = fmaf(v, f0.y, ay0);
            ax1 = fmaf(v, f1.x, ax1); ay1 = fmaf(v, f1.y, ay1);
        }
    }
    for (; j < end; ++j) {
        unsigned int u = cv[j];
        uint2 h = xv[(size_t)(u & 0x3FFFF) * 16 + d];
        float v = (float)(u >> 18) * QINV;
        __half2 h0, h1;
        __builtin_memcpy(&h0, &h.x, 4);
        __builtin_memcpy(&h1, &h.y, 4);
        float2 f0 = __half22float2(h0);
        float2 f1 = __half22float2(h1);
        ax0 = fmaf(v, f0.x, ax0); ay0 = fmaf(v, f0.y, ay0);
        ax1 = fmaf(v, f1.x, ax1); ay1 = fmaf(v, f1.y, ay1);
    }
    __half2 o0 = __floats2half2_rn(ax0, ay0);
    __half2 o1 = __floats2half2_rn(ax1, ay1);
    unsigned int w0, w1;
    __builtin_memcpy(&w0, &o0, 4);
    __builtin_memcpy(&w1, &o1, 4);
    unsigned long long ob = (unsigned long long)w0 |
                            ((unsigned long long)w1 << 32);
    __builtin_nontemporal_store(ob,
        (unsigned long long*)&y2[(size_t)r * 32 + 2 * d]);
}

// ---------------------------------------------------------------------------
// Layer-3 SpMM restricted to batch rows, quarter-wave structure.
// R10: FOLDS both batch_add kernels — the group owning entry b also adds
// X1 = xB[r] and X2 = xA[r] (weight 1) before the ACCB float4 RMW.
// ---------------------------------------------------------------------------
__global__ void spmm_batch(const int* __restrict__ rowptr,
                           const unsigned int* __restrict__ cv,
                           const __half2* __restrict__ xA,   // layer-2 table (gathered + X2 term)
                           const __half2* __restrict__ xB,   // layer-1 table (X1 term)
                           const int* __restrict__ users,
                           const int* __restrict__ items,
                           float* __restrict__ accb) {
    int lane = threadIdx.x & 63;
    int grp = lane >> 4;
    int d = lane & 15;
    int b = blockIdx.x * 16 + (threadIdx.x >> 6) * 4 + grp;
    if (b >= 2 * BATCH) return;
    const uint2* xv = (const uint2*)xA;
    const uint2* xv1 = (const uint2*)xB;
    int r = (b < BATCH) ? users[b] : (N_USERS + items[b - BATCH]);
    int beg = rowptr[r];
    int end = rowptr[r + 1];
    // start accumulators with the folded X1 + X2 terms
    uint2 tA = xv[(size_t)r * 16 + d];
    uint2 tB = xv1[(size_t)r * 16 + d];
    __half2 tA0, tA1, tB0, tB1;
    __builtin_memcpy(&tA0, &tA.x, 4);
    __builtin_memcpy(&tA1, &tA.y, 4);
    __builtin_memcpy(&tB0, &tB.x, 4);
    __builtin_memcpy(&tB1, &tB.y, 4);
    float2 fA0 = __half22float2(tA0), fA1 = __half22float2(tA1);
    float2 fB0 = __half22float2(tB0), fB1 = __half22float2(tB1);
    float ax0 = fA0.x + fB0.x, ay0 = fA0.y + fB0.y;
    float ax1 = fA1.x + fB1.x, ay1 = fA1.y + fB1.y;
    int j = beg;
    for (; j + 7 < end; j += 8) {
        unsigned int u[8];
        uint2 h[8];
        #pragma unroll
        for (int k = 0; k < 8; ++k) u[k] = cv[j + k];
        #pragma unroll
        for (int k = 0; k < 8; ++k) h[k] = xv[(size_t)(u[k] & 0x3FFFF) * 16 + d];
        #pragma unroll
        for (int k = 0; k < 8; ++k) {
            float v = (float)(u[k] >> 18) * QINV;
            __half2 h0, h1;
            __builtin_memcpy(&h0, &h[k].x, 4);
            __builtin_memcpy(&h1, &h[k].y, 4);
            float2 f0 = __half22float2(h0);
            float2 f1 = __half22float2(h1);
            ax0 = fmaf(v, f0.x, ax0); ay0 = fmaf(v, f0.y, ay0);
            ax1 = fmaf(v, f1.x, ax1); ay1 = fmaf(v, f1.y, ay1);
        }
    }
    for (; j + 3 < end; j += 4) {
        unsigned int u[4];
        uint2 h[4];
        #pragma unroll
        for (int k = 0; k < 4; ++k) u[k] = cv[j + k];
        #pragma unroll
        for (int k = 0; k < 4; ++k) h[k] = xv[(size_t)(u[k] & 0x3FFFF) * 16 + d];
        #pragma unroll
        for (int k = 0; k < 4; ++k) {
            float v = (float)(u[k] >> 18) * QINV;
            __half2 h0, h1;
            __builtin_memcpy(&h0, &h[k].x, 4);
            __builtin_memcpy(&h1, &h[k].y, 4);
            float2 f0 = __half22float2(h0);
            float2 f1 = __half22float2(h1);
            ax0 = fmaf(v, f0.x, ax0); ay0 = fmaf(v, f0.y, ay0);
            ax1 = fmaf(v, f1.x, ax1); ay1 = fmaf(v, f1.y, ay1);
        }
    }
    for (; j < end; ++j) {
        unsigned int u = cv[j];
        uint2 h = xv[(size_t)(u & 0x3FFFF) * 16 + d];
        float v = (float)(u >> 18) * QINV;
        __half2 h0, h1;
        __builtin_memcpy(&h0, &h.x, 4);
        __builtin_memcpy(&h1, &h.y, 4);
        float2 f0 = __half22float2(h0);
        float2 f1 = __half22float2(h1);
        ax0 = fmaf(v, f0.x, ax0); ay0 = fmaf(v, f0.y, ay0);
        ax1 = fmaf(v, f1.x, ax1); ay1 = fmaf(v, f1.y, ay1);
    }
    float4* a4 = (float4*)(accb + (size_t)b * 64 + 4 * d);
    float4 o = *a4;
    o.x += ax0; o.y += ay0; o.z += ax1; o.w += ay1;
    *a4 = o;
}

// ---------------------------------------------------------------------------
// Final dot: out[b] = (accb[b] . accb[BATCH+b]) / 16
// ---------------------------------------------------------------------------
__global__ void final_dot(const float* __restrict__ accb,
                          float* __restrict__ out) {
    int b = blockIdx.x * 4 + (threadIdx.x >> 6);
    int lane = threadIdx.x & 63;
    if (b >= BATCH) return;
    float pu = accb[(size_t)b * 64 + lane];
    float pi = accb[(size_t)(BATCH + b) * 64 + lane];
    float p = pu * pi;
    #pragma unroll
    for (int off = 32; off > 0; off >>= 1)
        p += __shfl_down(p, off, 64);
    if (lane == 0) out[b] = p * (1.0f / 16.0f);
}

extern "C" void kernel_launch(void* const* d_in, const int* in_sizes, int n_in,
                              void* d_out, int out_size, void* d_ws, size_t ws_size,
                              hipStream_t stream) {
    const float* uw   = (const float*)d_in[0];
    const float* iw   = (const float*)d_in[1];
    const float* tw   = (const float*)d_in[2];
    const float* vals = (const float*)d_in[3];
    const int*   row  = (const int*)d_in[4];
    const int*   col  = (const int*)d_in[5];
    const int*   users= (const int*)d_in[6];
    const int*   items= (const int*)d_in[7];
    float* out = (float*)d_out;

    // ---- workspace layout (no aliasing; ~96 MB total) ----
    char* ws = (char*)d_ws;
    const size_t NODE_F = (size_t)N_NODES * DIM;       // 9,664,000 elements
    __half* A     = (__half*)ws; ws += NODE_F * 2;     // 19.33 MB
    __half* B     = (__half*)ws; ws += NODE_F * 2;     // 19.33 MB
    float* ACCB   = (float*)ws;  ws += (size_t)2 * BATCH * DIM * 4;
    int*   bcnt   = (int*)ws;    ws += (size_t)NB * 4;
    int*   bptr   = (int*)ws;    ws += (size_t)(NB + 1) * 4;
    int*   rowptr = (int*)ws;    ws += (size_t)(N_NODES + 1) * 4;
    int*   hcnt   = (int*)ws;    ws += (size_t)NPART * NB * 4;   // 1.21 MB
    int*   sync   = (int*)ws;    ws += 64;                       // scanAB counter
    unsigned int* cv = (unsigned int*)ws; ws += (size_t)NNZ * 4; // 16 MB packed
    int2*  cvtmp  = (int2*)ws;   ws += (size_t)NNZ * 8;          // 32 MB

    // ---- phase0: count + concat + batch_init fused (also zeroes sync) ----
    phase0<<<NPART + CONCAT_BLOCKS + BINIT_BLOCKS, 1024, 0, stream>>>(
        (const float4*)uw, (const float4*)iw, (const float4*)tw, row,
        users, items, (__half2*)A, (float4*)ACCB, hcnt, sync);

    // ---- fused scan + LDS-sorted scatter + bucket sort -> CSR ----
    part_scanAB<<<NB / 4, 256, 0, stream>>>(hcnt, bcnt, bptr, rowptr, sync);
    part_scatter<<<NPART, 1024, 0, stream>>>(row, col, vals, hcnt, bptr, cvtmp);
    bucket_sort<<<NB, 512, 0, stream>>>(bptr, (const long long*)cvtmp, cv, rowptr);

    // ---- layers 1,2: full SpMM; layer 3 + folded batch adds; dot ----
    const int spmm_blocks = NB * 8;   // 1180 buckets x 8 sub-tiles (16 rows each)
    spmm_csr<<<spmm_blocks, 256, 0, stream>>>(rowptr, cv, (const __half2*)A,
                                              (__half2*)B);
    spmm_csr<<<spmm_blocks, 256, 0, stream>>>(rowptr, cv, (const __half2*)B,
                                              (__half2*)A);
    spmm_batch<<<(2 * BATCH + 15) / 16, 256, 0, stream>>>(
        rowptr, cv, (const __half2*)A, (const __half2*)B, users, items, ACCB);

    final_dot<<<(BATCH + 3) / 4, 256, 0, stream>>>(ACCB, out);
}

// Round 11
// 393.499 us; speedup vs baseline: 1.1342x; 1.0021x over previous
//
#include <hip/hip_runtime.h>
#include <hip/hip_fp16.h>

#define N_USERS 100000
#define N_ITEMS 50000
#define N_TOPICS 1000
#define N_NODES (N_USERS + N_ITEMS + N_TOPICS)   // 151000
#define DIM 64
#define NNZ 4000000
#define BATCH 16384

#define BROWS 128                                 // rows per bucket
#define NB ((N_NODES + BROWS - 1) / BROWS)        // 1180 buckets
#define NPART 256                                 // partition blocks
#define CHUNK ((NNZ + NPART - 1) / NPART)         // 15625 edges per block
#define SUB 7813                                  // LDS sort sub-chunk
#define SEGCAP 4608                               // LDS seg capacity

// cv entry: (qval14 << 18) | col18 ; val = qval * (1/16384)
#define QSCALE 16384.0f
#define QINV   6.103515625e-05f                   // 1/16384

#define CONCAT_TOTAL (N_NODES * (DIM / 4))        // 2,416,000
#define CONCAT_BLOCKS ((CONCAT_TOTAL + 1023) / 1024)   // 2360

// ---------------------------------------------------------------------------
// phase0: fused (part_count | concat_init) by blockIdx role.
// (R11: batch_init folded into spmm_batch.)
// ---------------------------------------------------------------------------
__global__ void __launch_bounds__(1024)
phase0(const float4* __restrict__ uw,
       const float4* __restrict__ iw,
       const float4* __restrict__ tw,
       const int* __restrict__ row,
       __half2* __restrict__ x0,
       int* __restrict__ hcnt,
       int* __restrict__ sync) {
    __shared__ int h[NB];
    const int blk = blockIdx.x;
    const int t = threadIdx.x;
    if (blk < NPART) {
        // ---- part_count role ----
        if (blk == 0 && t == 0) *sync = 0;
        for (int i = t; i < NB; i += 1024) h[i] = 0;
        __syncthreads();
        int e0 = blk * CHUNK;
        int e1 = e0 + CHUNK; if (e1 > NNZ) e1 = NNZ;
        for (int e = e0 + t; e < e1; e += 1024) {
            int r = __builtin_nontemporal_load(&row[e]);
            atomicAdd(&h[r >> 7], 1);
        }
        __syncthreads();
        int* dst = hcnt + (size_t)blk * NB;
        for (int i = t; i < NB; i += 1024) dst[i] = h[i];
    } else {
        // ---- concat_init role ----
        int tid = (blk - NPART) * 1024 + t;
        if (tid >= CONCAT_TOTAL) return;
        int node = tid >> 4;
        int q = tid & 15;
        float4 v;
        if (node < N_USERS)                v = uw[node * 16 + q];
        else if (node < N_USERS + N_ITEMS) v = iw[(node - N_USERS) * 16 + q];
        else                               v = tw[(node - N_USERS - N_ITEMS) * 16 + q];
        x0[tid * 2]     = __floats2half2_rn(v.x, v.y);
        x0[tid * 2 + 1] = __floats2half2_rn(v.z, v.w);
    }
}

// ---------------------------------------------------------------------------
// Fused scanA + scanB (last-block pattern). 295 blocks x 256 threads.
// ---------------------------------------------------------------------------
__global__ void __launch_bounds__(256)
part_scanAB(int* __restrict__ hcnt,
            int* __restrict__ bcnt,
            int* __restrict__ bptr,
            int* __restrict__ rowptr,
            int* __restrict__ sync) {
    const int t = threadIdx.x;
    const int lane = t & 63;
    const int wid = t >> 6;
    int b = blockIdx.x * 4 + wid;     // grid sized so b < NB always
    int carry = 0;
    for (int base = 0; base < NPART; base += 64) {
        int g = base + lane;
        int v = hcnt[(size_t)g * NB + b];
        int x = v;
        #pragma unroll
        for (int off = 1; off < 64; off <<= 1) {
            int y = __shfl_up(x, off, 64);
            if (lane >= off) x += y;
        }
        int tot = __shfl(x, 63, 64);
        hcnt[(size_t)g * NB + b] = carry + x - v;
        carry += tot;
    }
    if (lane == 0) bcnt[b] = carry;
    __syncthreads();
    __threadfence();
    __shared__ int lastFlag;
    if (t == 0) lastFlag = (atomicAdd(sync, 1) == (int)gridDim.x - 1);
    __syncthreads();
    if (!lastFlag) return;

    // ---- scanB over bcnt[0..NB) with 256 threads ----
    __shared__ int wsum[4];
    __shared__ int carry_s;
    if (t == 0) carry_s = 0;
    __syncthreads();
    for (int base = 0; base < NB; base += 256) {
        int i = base + t;
        int v = (i < NB) ? bcnt[i] : 0;
        int x = v;
        #pragma unroll
        for (int off = 1; off < 64; off <<= 1) {
            int y = __shfl_up(x, off, 64);
            if (lane >= off) x += y;
        }
        if (lane == 63) wsum[wid] = x;
        __syncthreads();
        int wbase = 0;
        for (int w = 0; w < wid; ++w) wbase += wsum[w];
        int excl = carry_s + wbase + (x - v);
        if (i < NB) bptr[i] = excl;
        __syncthreads();
        if (t == 255) carry_s = excl + v;
        __syncthreads();
    }
    if (t == 0) { bptr[NB] = NNZ; rowptr[N_NODES] = NNZ; }
}

// ---------------------------------------------------------------------------
// Partition phase 3: block-local counting sort -> DENSE writes.
// R11: rows staged in LDS in pass A (no row re-read in pass B); vals
// quantized at scatter; split 6-B output (cvK uint = row7|col18,
// cvV ushort = qval14). LDS ~108 KB -> 1 block/CU.
// ---------------------------------------------------------------------------
__global__ void __launch_bounds__(1024)
part_scatter(const int* __restrict__ row,
             const int* __restrict__ col,
             const float* __restrict__ vals,
             const int* __restrict__ hcnt,
             const int* __restrict__ bptr,
             unsigned int* __restrict__ cvK,
             unsigned short* __restrict__ cvV) {
    __shared__ int rStage[SUB];                // 31.25 KB
    __shared__ unsigned int sortedK[SUB];      // 31.25 KB
    __shared__ unsigned short sortedV[SUB];    // 15.6 KB
    __shared__ unsigned short bktSorted[SUB];  // 15.6 KB
    __shared__ int cnt_s[NB];
    __shared__ int cur_s[NB];
    __shared__ int gcur[NB];                   // running global dst per bucket
    __shared__ int wsum[16];
    __shared__ int carry_s;
    const int g = blockIdx.x;
    const int t = threadIdx.x;
    const int lane = t & 63;
    const int wid = t >> 6;
    const int* hoff = hcnt + (size_t)g * NB;
    for (int i = t; i < NB; i += 1024) gcur[i] = bptr[i] + hoff[i];
    int e0 = g * CHUNK;
    int e1 = e0 + CHUNK; if (e1 > NNZ) e1 = NNZ;

    for (int s0 = e0; s0 < e1; s0 += SUB) {
        int n = e1 - s0; if (n > SUB) n = SUB;
        for (int i = t; i < NB; i += 1024) cnt_s[i] = 0;
        if (t == 0) carry_s = 0;
        __syncthreads();
        // pass A: read rows once, stage, histogram
        for (int j = t; j < n; j += 1024) {
            int r = __builtin_nontemporal_load(&row[s0 + j]);
            rStage[j] = r;
            atomicAdd(&cnt_s[r >> 7], 1);
        }
        __syncthreads();
        // exclusive block-scan cnt_s -> cur_s (local bucket starts)
        for (int base = 0; base < NB; base += 1024) {
            int i = base + t;
            int v = (i < NB) ? cnt_s[i] : 0;
            int x = v;
            #pragma unroll
            for (int off = 1; off < 64; off <<= 1) {
                int y = __shfl_up(x, off, 64);
                if (lane >= off) x += y;
            }
            if (lane == 63) wsum[wid] = x;
            __syncthreads();
            int wbase = 0;
            for (int w = 0; w < wid; ++w) wbase += wsum[w];
            int excl = carry_s + wbase + (x - v);
            if (i < NB) cur_s[i] = excl;
            __syncthreads();
            if (t == 1023) carry_s = excl + v;
            __syncthreads();
        }
        // pass B: scatter into LDS in bucket-sorted order; quantize val
        for (int j = t; j < n; j += 1024) {
            int r = rStage[j];
            int c = __builtin_nontemporal_load(&col[s0 + j]);
            float v = __builtin_nontemporal_load(&vals[s0 + j]);
            unsigned int qv = (unsigned int)(v * QSCALE + 0.5f);
            if (qv > 16383u) qv = 16383u;
            int b = r >> 7;
            int p = atomicAdd(&cur_s[b], 1);
            sortedK[p] = (unsigned int)(((r & (BROWS - 1)) << 18) | c);
            sortedV[p] = (unsigned short)qv;
            bktSorted[p] = (unsigned short)b;
        }
        __syncthreads();
        // pass C: dense global write (local start = cur_s[b] - cnt_s[b]).
        for (int j = t; j < n; j += 1024) {
            int b = bktSorted[j];
            int lb = cur_s[b] - cnt_s[b];
            int dst = gcur[b] + (j - lb);
            cvK[dst] = sortedK[j];
            cvV[dst] = sortedV[j];
        }
        __syncthreads();
        for (int i = t; i < NB; i += 1024) gcur[i] += cnt_s[i];
        __syncthreads();
    }
}

// ---------------------------------------------------------------------------
// Bucket-local counting sort -> row-sorted CSR (cv, packed 4B) + rowptr.
// R11: consumes split 6-B (cvK,cvV); seg LDS 28 KB.
// ---------------------------------------------------------------------------
__global__ void __launch_bounds__(512)
bucket_sort(const int* __restrict__ bptr,
            const unsigned int* __restrict__ cvK,
            const unsigned short* __restrict__ cvV,
            unsigned int* __restrict__ cv,
            int* __restrict__ rowptr) {
    __shared__ unsigned int segK[SEGCAP];      // 18.4 KB
    __shared__ unsigned short segV[SEGCAP];    // 9.2 KB
    __shared__ int cnt[BROWS];
    __shared__ int cur[BROWS];
    const int t = threadIdx.x;
    const int b = blockIdx.x;
    const int beg = bptr[b];
    const int end = bptr[b + 1];
    const int n = end - beg;

    for (int i = t; i < BROWS; i += 512) cnt[i] = 0;
    const bool lds_path = (n <= SEGCAP);

    if (lds_path) {
        for (int j = t; j < n; j += 512) {
            segK[j] = __builtin_nontemporal_load(&cvK[beg + j]);
            segV[j] = __builtin_nontemporal_load(&cvV[beg + j]);
        }
    }
    __syncthreads();

    // pass 1: per-row counts
    if (lds_path) {
        for (int j = t; j < n; j += 512)
            atomicAdd(&cnt[(segK[j] >> 18) & (BROWS - 1)], 1);
    } else {
        for (int j = beg + t; j < end; j += 512)
            atomicAdd(&cnt[(cvK[j] >> 18) & (BROWS - 1)], 1);
    }
    __syncthreads();

    // exclusive scan of 128 counts on wave 0; also emit rowptr
    if (t < 64) {
        int lane = t;
        int v0 = cnt[lane];
        int v1 = cnt[64 + lane];
        int x0 = v0;
        #pragma unroll
        for (int off = 1; off < 64; off <<= 1) {
            int y = __shfl_up(x0, off, 64);
            if (lane >= off) x0 += y;
        }
        int tot0 = __shfl(x0, 63, 64);
        int x1 = v1;
        #pragma unroll
        for (int off = 1; off < 64; off <<= 1) {
            int y = __shfl_up(x1, off, 64);
            if (lane >= off) x1 += y;
        }
        x1 += tot0;
        int e0 = x0 - v0;
        int e1 = x1 - v1;
        cur[lane] = e0;
        cur[64 + lane] = e1;
        int rowbase = b * BROWS;
        if (rowbase + lane < N_NODES)      rowptr[rowbase + lane] = beg + e0;
        if (rowbase + 64 + lane < N_NODES) rowptr[rowbase + 64 + lane] = beg + e1;
    }
    __syncthreads();

    // pass 2: scatter into row-sorted order; strip row bits, pack qv|col
    if (lds_path) {
        for (int j = t; j < n; j += 512) {
            unsigned int k = segK[j];
            int p = atomicAdd(&cur[(k >> 18) & (BROWS - 1)], 1);
            cv[beg + p] = ((unsigned int)segV[j] << 18) | (k & 0x3FFFF);
        }
    } else {
        for (int j = beg + t; j < end; j += 512) {
            unsigned int k = cvK[j];
            unsigned int qv = cvV[j];
            int p = atomicAdd(&cur[(k >> 18) & (BROWS - 1)], 1);
            cv[beg + p] = (qv << 18) | (k & 0x3FFFF);
        }
    }
}

// ---------------------------------------------------------------------------
// SpMM over CSR, FP16 tables. QUARTER-WAVE PER ROW — wave = 4 adjacent
// rows, 16 lanes each; 8-B uint2 gathers; unroll 8/4/1; nt 8-B y-store.
// (At its structural wall: 214 MB fetch vs ~165 MB compulsory floor.)
// ---------------------------------------------------------------------------
__global__ void spmm_csr(const int* __restrict__ rowptr,
                         const unsigned int* __restrict__ cv,
                         const __half2* __restrict__ x2,
                         __half2* __restrict__ y2) {
    int bucket = blockIdx.x >> 3;
    int sub = blockIdx.x & 7;
    int lane = threadIdx.x & 63;
    int grp = lane >> 4;
    int d = lane & 15;
    int r = bucket * BROWS + sub * 16 + (threadIdx.x >> 6) * 4 + grp;
    if (r >= N_NODES) return;
    const uint2* xv = (const uint2*)x2;   // 16 uint2 per row
    int beg = rowptr[r];
    int end = rowptr[r + 1];
    float ax0 = 0.0f, ay0 = 0.0f, ax1 = 0.0f, ay1 = 0.0f;
    int j = beg;
    for (; j + 7 < end; j += 8) {         // 8 x 8B gathers in flight
        unsigned int u[8];
        uint2 h[8];
        #pragma unroll
        for (int k = 0; k < 8; ++k) u[k] = cv[j + k];
        #pragma unroll
        for (int k = 0; k < 8; ++k) h[k] = xv[(size_t)(u[k] & 0x3FFFF) * 16 + d];
        #pragma unroll
        for (int k = 0; k < 8; ++k) {
            float v = (float)(u[k] >> 18) * QINV;
            __half2 h0, h1;
            __builtin_memcpy(&h0, &h[k].x, 4);
            __builtin_memcpy(&h1, &h[k].y, 4);
            float2 f0 = __half22float2(h0);
            float2 f1 = __half22float2(h1);
            ax0 = fmaf(v, f0.x, ax0); ay0 = fmaf(v, f0.y, ay0);
            ax1 = fmaf(v, f1.x, ax1); ay1 = fmaf(v, f1.y, ay1);
        }
    }
    for (; j + 3 < end; j += 4) {
        unsigned int u[4];
        uint2 h[4];
        #pragma unroll
        for (int k = 0; k < 4; ++k) u[k] = cv[j + k];
        #pragma unroll
        for (int k = 0; k < 4; ++k) h[k] = xv[(size_t)(u[k] & 0x3FFFF) * 16 + d];
        #pragma unroll
        for (int k = 0; k < 4; ++k) {
            float v = (float)(u[k] >> 18) * QINV;
            __half2 h0, h1;
            __builtin_memcpy(&h0, &h[k].x, 4);
            __builtin_memcpy(&h1, &h[k].y, 4);
            float2 f0 = __half22float2(h0);
            float2 f1 = __half22float2(h1);
            ax0 = fmaf(v, f0.x, ax0); ay0 = fmaf(v, f0.y, ay0);
            ax1 = fmaf(v, f1.x, ax1); ay1 = fmaf(v, f1.y, ay1);
        }
    }
    for (; j < end; ++j) {
        unsigned int u = cv[j];
        uint2 h = xv[(size_t)(u & 0x3FFFF) * 16 + d];
        float v = (float)(u >> 18) * QINV;
        __half2 h0, h1;
        __builtin_memcpy(&h0, &h.x, 4);
        __builtin_memcpy(&h1, &h.y, 4);
        float2 f0 = __half22float2(h0);
        float2 f1 = __half22float2(h1);
        ax0 = fmaf(v, f0.x, ax0); ay0 = fmaf(v, f0.y, ay0);
        ax1 = fmaf(v, f1.x, ax1); ay1 = fmaf(v, f1.y, ay1);
    }
    __half2 o0 = __floats2half2_rn(ax0, ay0);
    __half2 o1 = __floats2half2_rn(ax1, ay1);
    unsigned int w0, w1;
    __builtin_memcpy(&w0, &o0, 4);
    __builtin_memcpy(&w1, &o1, 4);
    unsigned long long ob = (unsigned long long)w0 |
                            ((unsigned long long)w1 << 32);
    __builtin_nontemporal_store(ob,
        (unsigned long long*)&y2[(size_t)r * 32 + 2 * d]);
}

// ---------------------------------------------------------------------------
// Layer-3 SpMM restricted to batch rows, quarter-wave structure.
// R11: also folds X0 (exact fp32 gather from weight tables) — ACCB
// becomes a pure store (batch_init kernel-role removed).
// ---------------------------------------------------------------------------
__global__ void spmm_batch(const int* __restrict__ rowptr,
                           const unsigned int* __restrict__ cv,
                           const __half2* __restrict__ xA,   // layer-2 table
                           const __half2* __restrict__ xB,   // layer-1 table
                           const float4* __restrict__ uw,
                           const float4* __restrict__ iw,
                           const int* __restrict__ users,
                           const int* __restrict__ items,
                           float* __restrict__ accb) {
    int lane = threadIdx.x & 63;
    int grp = lane >> 4;
    int d = lane & 15;
    int b = blockIdx.x * 16 + (threadIdx.x >> 6) * 4 + grp;
    if (b >= 2 * BATCH) return;
    const uint2* xv = (const uint2*)xA;
    const uint2* xv1 = (const uint2*)xB;
    int r;
    float4 x0;
    if (b < BATCH) { int u = users[b]; r = u; x0 = uw[(size_t)u * 16 + d]; }
    else { int it = items[b - BATCH]; r = N_USERS + it; x0 = iw[(size_t)it * 16 + d]; }
    int beg = rowptr[r];
    int end = rowptr[r + 1];
    // init accumulators with X0 (fp32 exact) + X1[r] + X2[r]
    uint2 tA = xv[(size_t)r * 16 + d];
    uint2 tB = xv1[(size_t)r * 16 + d];
    __half2 tA0, tA1, tB0, tB1;
    __builtin_memcpy(&tA0, &tA.x, 4);
    __builtin_memcpy(&tA1, &tA.y, 4);
    __builtin_memcpy(&tB0, &tB.x, 4);
    __builtin_memcpy(&tB1, &tB.y, 4);
    float2 fA0 = __half22float2(tA0), fA1 = __half22float2(tA1);
    float2 fB0 = __half22float2(tB0), fB1 = __half22float2(tB1);
    float ax0 = x0.x + fA0.x + fB0.x, ay0 = x0.y + fA0.y + fB0.y;
    float ax1 = x0.z + fA1.x + fB1.x, ay1 = x0.w + fA1.y + fB1.y;
    int j = beg;
    for (; j + 7 < end; j += 8) {
        unsigned int u[8];
        uint2 h[8];
        #pragma unroll
        for (int k = 0; k < 8; ++k) u[k] = cv[j + k];
        #pragma unroll
        for (int k = 0; k < 8; ++k) h[k] = xv[(size_t)(u[k] & 0x3FFFF) * 16 + d];
        #pragma unroll
        for (int k = 0; k < 8; ++k) {
            float v = (float)(u[k] >> 18) * QINV;
            __half2 h0, h1;
            __builtin_memcpy(&h0, &h[k].x, 4);
            __builtin_memcpy(&h1, &h[k].y, 4);
            float2 f0 = __half22float2(h0);
            float2 f1 = __half22float2(h1);
            ax0 = fmaf(v, f0.x, ax0); ay0 = fmaf(v, f0.y, ay0);
            ax1 = fmaf(v, f1.x, ax1); ay1 = fmaf(v, f1.y, ay1);
        }
    }
    for (; j + 3 < end; j += 4) {
        unsigned int u[4];
        uint2 h[4];
        #pragma unroll
        for (int k = 0; k < 4; ++k) u[k] = cv[j + k];
        #pragma unroll
        for (int k = 0; k < 4; ++k) h[k] = xv[(size_t)(u[k] & 0x3FFFF) * 16 + d];
        #pragma unroll
        for (int k = 0; k < 4; ++k) {
            float v = (float)(u[k] >> 18) * QINV;
            __half2 h0, h1;
            __builtin_memcpy(&h0, &h[k].x, 4);
            __builtin_memcpy(&h1, &h[k].y, 4);
            float2 f0 = __half22float2(h0);
            float2 f1 = __half22float2(h1);
            ax0 = fmaf(v, f0.x, ax0); ay0 = fmaf(v, f0.y, ay0);
            ax1 = fmaf(v, f1.x, ax1); ay1 = fmaf(v, f1.y, ay1);
        }
    }
    for (; j < end; ++j) {
        unsigned int u = cv[j];
        uint2 h = xv[(size_t)(u & 0x3FFFF) * 16 + d];
        float v = (float)(u >> 18) * QINV;
        __half2 h0, h1;
        __builtin_memcpy(&h0, &h.x, 4);
        __builtin_memcpy(&h1, &h.y, 4);
        float2 f0 = __half22float2(h0);
        float2 f1 = __half22float2(h1);
        ax0 = fmaf(v, f0.x, ax0); ay0 = fmaf(v, f0.y, ay0);
        ax1 = fmaf(v, f1.x, ax1); ay1 = fmaf(v, f1.y, ay1);
    }
    float4* a4 = (float4*)(accb + (size_t)b * 64 + 4 * d);
    *a4 = make_float4(ax0, ay0, ax1, ay1);   // pure store (no RMW)
}

// ---------------------------------------------------------------------------
// Final dot: out[b] = (accb[b] . accb[BATCH+b]) / 16
// ---------------------------------------------------------------------------
__global__ void final_dot(const float* __restrict__ accb,
                          float* __restrict__ out) {
    int b = blockIdx.x * 4 + (threadIdx.x >> 6);
    int lane = threadIdx.x & 63;
    if (b >= BATCH) return;
    float pu = accb[(size_t)b * 64 + lane];
    float pi = accb[(size_t)(BATCH + b) * 64 + lane];
    float p = pu * pi;
    #pragma unroll
    for (int off = 32; off > 0; off >>= 1)
        p += __shfl_down(p, off, 64);
    if (lane == 0) out[b] = p * (1.0f / 16.0f);
}

extern "C" void kernel_launch(void* const* d_in, const int* in_sizes, int n_in,
                              void* d_out, int out_size, void* d_ws, size_t ws_size,
                              hipStream_t stream) {
    const float* uw   = (const float*)d_in[0];
    const float* iw   = (const float*)d_in[1];
    const float* tw   = (const float*)d_in[2];
    const float* vals = (const float*)d_in[3];
    const int*   row  = (const int*)d_in[4];
    const int*   col  = (const int*)d_in[5];
    const int*   users= (const int*)d_in[6];
    const int*   items= (const int*)d_in[7];
    float* out = (float*)d_out;

    // ---- workspace layout (no aliasing; ~88 MB total) ----
    char* ws = (char*)d_ws;
    const size_t NODE_F = (size_t)N_NODES * DIM;       // 9,664,000 elements
    __half* A     = (__half*)ws; ws += NODE_F * 2;     // 19.33 MB
    __half* B     = (__half*)ws; ws += NODE_F * 2;     // 19.33 MB
    float* ACCB   = (float*)ws;  ws += (size_t)2 * BATCH * DIM * 4;
    int*   bcnt   = (int*)ws;    ws += (size_t)NB * 4;
    int*   bptr   = (int*)ws;    ws += (size_t)(NB + 1) * 4;
    int*   rowptr = (int*)ws;    ws += (size_t)(N_NODES + 1) * 4;
    int*   hcnt   = (int*)ws;    ws += (size_t)NPART * NB * 4;   // 1.21 MB
    int*   sync   = (int*)ws;    ws += 64;                       // scanAB counter
    unsigned int* cv  = (unsigned int*)ws;  ws += (size_t)NNZ * 4; // 16 MB packed
    unsigned int* cvK = (unsigned int*)ws;  ws += (size_t)NNZ * 4; // 16 MB keys
    unsigned short* cvV = (unsigned short*)ws; ws += (size_t)NNZ * 2; // 8 MB qvals

    // ---- phase0: count + concat fused (also zeroes sync) ----
    phase0<<<NPART + CONCAT_BLOCKS, 1024, 0, stream>>>(
        (const float4*)uw, (const float4*)iw, (const float4*)tw, row,
        (__half2*)A, hcnt, sync);

    // ---- fused scan + LDS-sorted scatter + bucket sort -> CSR ----
    part_scanAB<<<NB / 4, 256, 0, stream>>>(hcnt, bcnt, bptr, rowptr, sync);
    part_scatter<<<NPART, 1024, 0, stream>>>(row, col, vals, hcnt, bptr, cvK, cvV);
    bucket_sort<<<NB, 512, 0, stream>>>(bptr, cvK, cvV, cv, rowptr);

    // ---- layers 1,2: full SpMM; layer 3 + folded X0/X1/X2 terms; dot ----
    const int spmm_blocks = NB * 8;   // 1180 buckets x 8 sub-tiles (16 rows each)
    spmm_csr<<<spmm_blocks, 256, 0, stream>>>(rowptr, cv, (const __half2*)A,
                                              (__half2*)B);
    spmm_csr<<<spmm_blocks, 256, 0, stream>>>(rowptr, cv, (const __half2*)B,
                                              (__half2*)A);
    spmm_batch<<<(2 * BATCH + 15) / 16, 256, 0, stream>>>(
        rowptr, cv, (const __half2*)A, (const __half2*)B,
        (const float4*)uw, (const float4*)iw, users, items, ACCB);

    final_dot<<<(BATCH + 3) / 4, 256, 0, stream>>>(ACCB, out);
}